// Round 7
// baseline (324.327 us; speedup 1.0000x reference)
//
#include <hip/hip_runtime.h>
#include <math.h>

#define BB    16
#define PROBN 2048
#define POMO  256
#define ED    128
#define HN    8
#define DDIM  16
#define NEXP  8

// ws float offsets (total ~10.23M floats = ~40.9 MB)
#define WS_K     0
#define WS_V     (WS_K + BB*PROBN*ED)
#define WS_Q     (WS_V + BB*PROBN*ED)
#define WS_OUT   (WS_Q + BB*POMO*ED)
#define WS_MH    (WS_OUT + BB*POMO*ED)
#define WS_WC    (WS_MH + BB*POMO*ED)
#define WS_BC    (WS_WC + BB*ED*ED)
#define WS_GATES (WS_BC + BB*ED)

// ---------------------------------------------------------------------------
// K1: gating (top-2 softmax), gates -> ws, moe_loss -> d_out tail
// ---------------------------------------------------------------------------
__global__ __launch_bounds__(128) void k_gating(
    const float* __restrict__ mid, const float* __restrict__ w_gate,
    float* __restrict__ gates_ws, float* __restrict__ moe_out)
{
  __shared__ float lg[BB][NEXP];
  __shared__ float gt[BB][NEXP];
  int t = threadIdx.x;
  {
    int b = t >> 3, e = t & 7;
    float acc = 0.f;
    #pragma unroll 8
    for (int k = 0; k < ED; ++k) acc += mid[b*ED + k] * w_gate[k*NEXP + e];
    lg[b][e] = acc;
  }
  __syncthreads();
  if (t < BB) {
    int b = t;
    int i1 = 0; float v1 = lg[b][0];
    #pragma unroll
    for (int e = 1; e < NEXP; ++e) if (lg[b][e] > v1) { v1 = lg[b][e]; i1 = e; }
    int i2 = -1; float v2 = -3.0e38f;
    #pragma unroll
    for (int e = 0; e < NEXP; ++e) if (e != i1 && lg[b][e] > v2) { v2 = lg[b][e]; i2 = e; }
    float e2 = __expf(v2 - v1);          // <= 1
    float g1 = 1.f / (1.f + e2);
    #pragma unroll
    for (int e = 0; e < NEXP; ++e) gt[b][e] = 0.f;
    gt[b][i1] = g1;
    gt[b][i2] = e2 * g1;
  }
  __syncthreads();
  if (t < BB*NEXP) gates_ws[t] = gt[t >> 3][t & 7];
  if (t == 0) {
    float imp[NEXP], ldc[NEXP];
    #pragma unroll
    for (int e = 0; e < NEXP; ++e) { imp[e] = 0.f; ldc[e] = 0.f; }
    for (int b = 0; b < BB; ++b)
      #pragma unroll
      for (int e = 0; e < NEXP; ++e) {
        float g = gt[b][e];
        imp[e] += g;
        if (g > 0.f) ldc[e] += 1.f;
      }
    float im = 0.f, lm = 0.f;
    #pragma unroll
    for (int e = 0; e < NEXP; ++e) { im += imp[e]; lm += ldc[e]; }
    im *= 0.125f; lm *= 0.125f;
    float iv = 0.f, lv = 0.f;
    #pragma unroll
    for (int e = 0; e < NEXP; ++e) {
      float a = imp[e] - im; iv += a*a;
      float c = ldc[e] - lm; lv += c*c;
    }
    iv *= 0.125f; lv *= 0.125f;
    moe_out[0] = iv / (im*im + 1e-10f) + lv / (lm*lm + 1e-10f);
  }
}

// ---------------------------------------------------------------------------
// K2: combined expert weights per batch: WC[b] = sum_e g_e * expert_W[e]
// ---------------------------------------------------------------------------
__global__ __launch_bounds__(256) void k_experts(
    const float* __restrict__ gates, const float* __restrict__ eW,
    const float* __restrict__ eB, float* __restrict__ WC, float* __restrict__ BC)
{
  __shared__ float g[NEXP];
  int tid = threadIdx.x, b = blockIdx.x;
  if (tid < NEXP) g[tid] = gates[b*NEXP + tid];
  __syncthreads();
  for (int i = tid; i < ED*ED; i += 256) {
    float a = 0.f;
    #pragma unroll
    for (int e = 0; e < NEXP; ++e) a += g[e] * eW[e*ED*ED + i];
    WC[b*ED*ED + i] = a;
  }
  if (tid < ED) {
    float a = 0.f;
    #pragma unroll
    for (int e = 0; e < NEXP; ++e) a += g[e] * eB[e*ED + tid];
    BC[b*ED + tid] = a;
  }
}

// ---------------------------------------------------------------------------
// K3: K = nodes@Wk, V = nodes@Wv   (32768x128 @ 128x128, x2, shared A tile)
// ---------------------------------------------------------------------------
__global__ __launch_bounds__(256) void k_kv(
    const float* __restrict__ nodes, const float* __restrict__ Wk,
    const float* __restrict__ Wv, float* __restrict__ Kp, float* __restrict__ Vp)
{
  __shared__ __align__(16) float As[64*132];
  __shared__ __align__(16) float Wks[32*128];
  __shared__ __align__(16) float Wvs[32*128];
  int tid = threadIdx.x;
  int r0 = blockIdx.x * 64;
  #pragma unroll
  for (int j = 0; j < 8; ++j) {
    int idx = tid + j*256;
    int row = idx >> 5, c4 = (idx & 31) << 2;
    *(float4*)&As[row*132 + c4] = *(const float4*)&nodes[(size_t)(r0 + row)*ED + c4];
  }
  int colg = tid & 15, rowg = tid >> 4;
  int c0 = colg << 2;              // cols c0..c0+3 and c0+64..c0+67
  float accK[4][8], accV[4][8];
  #pragma unroll
  for (int i = 0; i < 4; ++i)
    #pragma unroll
    for (int j = 0; j < 8; ++j) { accK[i][j] = 0.f; accV[i][j] = 0.f; }

  for (int kk = 0; kk < 128; kk += 32) {
    __syncthreads();
    #pragma unroll
    for (int j = 0; j < 4; ++j) {
      int idx = tid + j*256;
      int row = idx >> 5, c4 = (idx & 31) << 2;
      *(float4*)&Wks[row*128 + c4] = *(const float4*)&Wk[(kk + row)*ED + c4];
      *(float4*)&Wvs[row*128 + c4] = *(const float4*)&Wv[(kk + row)*ED + c4];
    }
    __syncthreads();
    #pragma unroll 4
    for (int k = 0; k < 32; ++k) {
      float a[4];
      #pragma unroll
      for (int i = 0; i < 4; ++i) a[i] = As[(rowg*4 + i)*132 + kk + k];
      float4 wk0 = *(float4*)&Wks[k*128 + c0];
      float4 wk1 = *(float4*)&Wks[k*128 + c0 + 64];
      float4 wv0 = *(float4*)&Wvs[k*128 + c0];
      float4 wv1 = *(float4*)&Wvs[k*128 + c0 + 64];
      #pragma unroll
      for (int i = 0; i < 4; ++i) {
        accK[i][0] += a[i]*wk0.x; accK[i][1] += a[i]*wk0.y;
        accK[i][2] += a[i]*wk0.z; accK[i][3] += a[i]*wk0.w;
        accK[i][4] += a[i]*wk1.x; accK[i][5] += a[i]*wk1.y;
        accK[i][6] += a[i]*wk1.z; accK[i][7] += a[i]*wk1.w;
        accV[i][0] += a[i]*wv0.x; accV[i][1] += a[i]*wv0.y;
        accV[i][2] += a[i]*wv0.z; accV[i][3] += a[i]*wv0.w;
        accV[i][4] += a[i]*wv1.x; accV[i][5] += a[i]*wv1.y;
        accV[i][6] += a[i]*wv1.z; accV[i][7] += a[i]*wv1.w;
      }
    }
  }
  #pragma unroll
  for (int i = 0; i < 4; ++i) {
    size_t row = (size_t)(r0 + rowg*4 + i) * ED;
    *(float4*)&Kp[row + c0]      = make_float4(accK[i][0], accK[i][1], accK[i][2], accK[i][3]);
    *(float4*)&Kp[row + c0 + 64] = make_float4(accK[i][4], accK[i][5], accK[i][6], accK[i][7]);
    *(float4*)&Vp[row + c0]      = make_float4(accV[i][0], accV[i][1], accV[i][2], accV[i][3]);
    *(float4*)&Vp[row + c0 + 64] = make_float4(accV[i][4], accV[i][5], accV[i][6], accV[i][7]);
  }
}

// ---------------------------------------------------------------------------
// K4: Q = [last, load] @ Wq_last   (4096x129 @ 129x128)
// ---------------------------------------------------------------------------
__global__ __launch_bounds__(256) void k_q(
    const float* __restrict__ last, const float* __restrict__ loadv,
    const float* __restrict__ Wq, float* __restrict__ Qp)
{
  __shared__ __align__(16) float As[32*132];
  __shared__ __align__(16) float Ws[129*128];
  int tid = threadIdx.x;
  int r0 = blockIdx.x * 32;
  #pragma unroll
  for (int j = 0; j < 4; ++j) {
    int idx = tid + j*256;
    int row = idx >> 5, c4 = (idx & 31) << 2;
    *(float4*)&As[row*132 + c4] = *(const float4*)&last[(size_t)(r0 + row)*ED + c4];
  }
  if (tid < 32) As[tid*132 + 128] = loadv[r0 + tid];
  for (int idx = tid; idx < 4128; idx += 256)
    *(float4*)&Ws[idx*4] = *(const float4*)&Wq[idx*4];
  __syncthreads();

  int colg = tid & 15, rowg = tid >> 4;
  int c0 = colg << 2;
  float acc[2][8];
  #pragma unroll
  for (int i = 0; i < 2; ++i)
    #pragma unroll
    for (int j = 0; j < 8; ++j) acc[i][j] = 0.f;
  #pragma unroll 4
  for (int k = 0; k < 129; ++k) {
    float a0 = As[(rowg*2)*132 + k];
    float a1 = As[(rowg*2 + 1)*132 + k];
    float4 w0 = *(float4*)&Ws[k*128 + c0];
    float4 w1 = *(float4*)&Ws[k*128 + c0 + 64];
    acc[0][0] += a0*w0.x; acc[0][1] += a0*w0.y; acc[0][2] += a0*w0.z; acc[0][3] += a0*w0.w;
    acc[0][4] += a0*w1.x; acc[0][5] += a0*w1.y; acc[0][6] += a0*w1.z; acc[0][7] += a0*w1.w;
    acc[1][0] += a1*w0.x; acc[1][1] += a1*w0.y; acc[1][2] += a1*w0.z; acc[1][3] += a1*w0.w;
    acc[1][4] += a1*w1.x; acc[1][5] += a1*w1.y; acc[1][6] += a1*w1.z; acc[1][7] += a1*w1.w;
  }
  #pragma unroll
  for (int i = 0; i < 2; ++i) {
    size_t row = (size_t)(r0 + rowg*2 + i) * ED;
    *(float4*)&Qp[row + c0]      = make_float4(acc[i][0], acc[i][1], acc[i][2], acc[i][3]);
    *(float4*)&Qp[row + c0 + 64] = make_float4(acc[i][4], acc[i][5], acc[i][6], acc[i][7]);
  }
}

// ---------------------------------------------------------------------------
// K5 v6 = R3/R6 body with KVBLK=256 (two 128-row halves per staged tile).
// Rationale: barrier+vmcnt-drain count halves (32 -> 15) while thread mapping,
// scalar mask loads, constant-per-thread swizzle, and the unconditional
// per-half rescale stay byte-identical to the proven 112-us version.
// LDS 41 KB -> 3 blocks/CU (was ~2.8 effective). Live regs unchanged.
// DO NOT add: reg prefetch across compute, quad-key float4 mask map,
// defer-max branch — each correlated with GB-scale scratch (R2/R4/R5).
// Guard: WRITE_SIZE must stay KB-scale.
// ---------------------------------------------------------------------------
__global__ __launch_bounds__(256, 4) void k_attn(
    const float* __restrict__ Kp, const float* __restrict__ Vp,
    const float* __restrict__ Qp, const float* __restrict__ mask,
    float* __restrict__ Op)
{
  __shared__ __align__(16) float kt[256*20];
  __shared__ __align__(16) float vt[256*20];
  int tid = threadIdx.x;
  int h = blockIdx.x & 7, b = blockIdx.x >> 3;
  int ph = blockIdx.y;
  int nq = tid & 15;          // 16 stripes, rows nq + 16*i within a half
  int pg = tid >> 4;          // 16 groups x 2 queries = 32 q/block
  int prow0 = b*POMO + ph*32 + pg*2;
  const float* maskb = mask + (size_t)prow0 * PROBN;
  const float* Kb = Kp + (size_t)b*PROBN*ED + h*16;
  const float* Vb = Vp + (size_t)b*PROBN*ED + h*16;

  float q[2][16];
  #pragma unroll
  for (int qi = 0; qi < 2; ++qi)
    #pragma unroll
    for (int d4 = 0; d4 < 4; ++d4) {
      float4 t = *(const float4*)&Qp[(size_t)(prow0 + qi)*ED + h*16 + d4*4];
      q[qi][4*d4+0] = t.x; q[qi][4*d4+1] = t.y; q[qi][4*d4+2] = t.z; q[qi][4*d4+3] = t.w;
    }
  float m[2], l[2], acc[2][16];
  #pragma unroll
  for (int qi = 0; qi < 2; ++qi) {
    m[qi] = -1.0e30f; l[qi] = 0.f;
    #pragma unroll
    for (int dd = 0; dd < 16; ++dd) acc[qi][dd] = 0.f;
  }

  // staging geometry: thread covers rows (tid>>2)+{0,64,128,192}, 16B at sd4
  int srow0 = tid >> 2, sd4 = (tid & 3) << 2;
  int sw = ((nq >> 3) & 1) << 2;

  for (int tile = 0; tile < 8; ++tile) {
    int t0 = tile << 8;
    if (tile > 0) __syncthreads();     // previous tile fully consumed
    // ---- stage 256-row K/V tile (4 rows per thread, one batch) ----
    #pragma unroll
    for (int rr = 0; rr < 4; ++rr) {
      int row = srow0 + rr*64;
      int sp = sd4 ^ (((row >> 3) & 1) << 2);
      *(float4*)&kt[row*20 + sp] = *(const float4*)&Kb[(size_t)(t0 + row)*ED + sd4];
      *(float4*)&vt[row*20 + sp] = *(const float4*)&Vb[(size_t)(t0 + row)*ED + sd4];
    }
    __syncthreads();

    #pragma unroll
    for (int h2 = 0; h2 < 2; ++h2) {
      int base = t0 + (h2 << 7);       // global col base of this half
      int lbase = h2 << 7;             // LDS row base of this half
      // ---- scores: s[q][i] = q . K[nq+16i] * 0.25 + mask ----
      float s[2][8];
      #pragma unroll
      for (int qi = 0; qi < 2; ++qi)
        #pragma unroll
        for (int i = 0; i < 8; ++i)
          s[qi][i] = maskb[(size_t)qi*PROBN + base + nq + 16*i];
      #pragma unroll
      for (int i = 0; i < 8; ++i) {
        int nl = lbase + nq + 16*i;
        float kr[16];
        #pragma unroll
        for (int D4 = 0; D4 < 4; ++D4) {
          float4 kv = *(float4*)&kt[nl*20 + ((D4 << 2) ^ sw)];
          kr[4*D4+0] = kv.x; kr[4*D4+1] = kv.y; kr[4*D4+2] = kv.z; kr[4*D4+3] = kv.w;
        }
        #pragma unroll
        for (int qi = 0; qi < 2; ++qi) {
          float d = 0.f;
          #pragma unroll
          for (int dd = 0; dd < 16; ++dd) d += q[qi][dd] * kr[dd];
          s[qi][i] += d * 0.25f;
        }
      }
      // ---- per-half max merge + single rescale ----
      #pragma unroll
      for (int qi = 0; qi < 2; ++qi) {
        float tm = s[qi][0];
        #pragma unroll
        for (int i = 1; i < 8; ++i) tm = fmaxf(tm, s[qi][i]);
        float M = fmaxf(m[qi], tm);
        float c = __expf(m[qi] - M);
        m[qi] = M;
        l[qi] *= c;
        #pragma unroll
        for (int dd = 0; dd < 16; ++dd) acc[qi][dd] *= c;
      }
      // ---- exp + PV accumulate ----
      #pragma unroll
      for (int i = 0; i < 8; ++i) {
        int nl = lbase + nq + 16*i;
        float vr[16];
        #pragma unroll
        for (int D4 = 0; D4 < 4; ++D4) {
          float4 vv = *(float4*)&vt[nl*20 + ((D4 << 2) ^ sw)];
          vr[4*D4+0] = vv.x; vr[4*D4+1] = vv.y; vr[4*D4+2] = vv.z; vr[4*D4+3] = vv.w;
        }
        #pragma unroll
        for (int qi = 0; qi < 2; ++qi) {
          float w = __expf(s[qi][i] - m[qi]);
          l[qi] += w;
          #pragma unroll
          for (int dd = 0; dd < 16; ++dd) acc[qi][dd] += w * vr[dd];
        }
      }
    }
  }

  // merge 16 stripes (tid bits 0..3, within wave)
  #pragma unroll
  for (int off = 1; off < 16; off <<= 1) {
    #pragma unroll
    for (int qi = 0; qi < 2; ++qi) {
      float m2 = __shfl_xor(m[qi], off);
      float l2 = __shfl_xor(l[qi], off);
      float M = fmaxf(m[qi], m2);
      float c1 = __expf(m[qi] - M), c2 = __expf(m2 - M);
      l[qi] = l[qi]*c1 + l2*c2;
      m[qi] = M;
      #pragma unroll
      for (int dd = 0; dd < 16; ++dd) {
        float a2 = __shfl_xor(acc[qi][dd], off);
        acc[qi][dd] = acc[qi][dd]*c1 + a2*c2;
      }
    }
  }
  // write: lanes nq<4, compile-time indexed via unrolled-if (rule #20)
  #pragma unroll
  for (int d4 = 0; d4 < 4; ++d4) {
    if (nq == d4) {
      #pragma unroll
      for (int qi = 0; qi < 2; ++qi) {
        float rl = 1.f / l[qi];
        *(float4*)&Op[(size_t)(prow0 + qi)*ED + h*16 + d4*4] =
          make_float4(acc[qi][4*d4+0]*rl, acc[qi][4*d4+1]*rl,
                      acc[qi][4*d4+2]*rl, acc[qi][4*d4+3]*rl);
      }
    }
  }
}

// ---------------------------------------------------------------------------
// K6: MH = OUT @ WC[b] + BC[b]   (per-batch 256x128 @ 128x128)
// ---------------------------------------------------------------------------
__global__ __launch_bounds__(256) void k_mh(
    const float* __restrict__ Op, const float* __restrict__ WC,
    const float* __restrict__ BC, float* __restrict__ MH)
{
  __shared__ __align__(16) float As[32*132];
  __shared__ __align__(16) float Ws[128*128];
  int tid = threadIdx.x;
  int b = blockIdx.x >> 3;
  int pt = blockIdx.x & 7;
  int r0 = b*POMO + pt*32;
  #pragma unroll
  for (int j = 0; j < 4; ++j) {
    int idx = tid + j*256;
    int row = idx >> 5, c4 = (idx & 31) << 2;
    *(float4*)&As[row*132 + c4] = *(const float4*)&Op[(size_t)(r0 + row)*ED + c4];
  }
  for (int idx = tid; idx < 4096; idx += 256)
    *(float4*)&Ws[idx*4] = *(const float4*)&WC[(size_t)b*ED*ED + idx*4];
  __syncthreads();

  int colg = tid & 15, rowg = tid >> 4;
  int c0 = colg << 2;
  float4 b0 = *(const float4*)&BC[b*ED + c0];
  float4 b1 = *(const float4*)&BC[b*ED + c0 + 64];
  float acc[2][8];
  #pragma unroll
  for (int i = 0; i < 2; ++i) {
    acc[i][0] = b0.x; acc[i][1] = b0.y; acc[i][2] = b0.z; acc[i][3] = b0.w;
    acc[i][4] = b1.x; acc[i][5] = b1.y; acc[i][6] = b1.z; acc[i][7] = b1.w;
  }
  #pragma unroll 4
  for (int k = 0; k < 128; ++k) {
    float a0 = As[(rowg*2)*132 + k];
    float a1 = As[(rowg*2 + 1)*132 + k];
    float4 w0 = *(float4*)&Ws[k*128 + c0];
    float4 w1 = *(float4*)&Ws[k*128 + c0 + 64];
    acc[0][0] += a0*w0.x; acc[0][1] += a0*w0.y; acc[0][2] += a0*w0.z; acc[0][3] += a0*w0.w;
    acc[0][4] += a0*w1.x; acc[0][5] += a0*w1.y; acc[0][6] += a0*w1.z; acc[0][7] += a0*w1.w;
    acc[1][0] += a1*w0.x; acc[1][1] += a1*w0.y; acc[1][2] += a1*w0.z; acc[1][3] += a1*w0.w;
    acc[1][4] += a1*w1.x; acc[1][5] += a1*w1.y; acc[1][6] += a1*w1.z; acc[1][7] += a1*w1.w;
  }
  #pragma unroll
  for (int i = 0; i < 2; ++i) {
    size_t row = (size_t)(r0 + rowg*2 + i) * ED;
    *(float4*)&MH[row + c0]      = make_float4(acc[i][0], acc[i][1], acc[i][2], acc[i][3]);
    *(float4*)&MH[row + c0 + 64] = make_float4(acc[i][4], acc[i][5], acc[i][6], acc[i][7]);
  }
}

// ---------------------------------------------------------------------------
// K7 v2: score2 = MH @ nodes^T / sqrt(E); probs = softmax(10*tanh + mask)
// phase 1: logits [8][2048] into LDS; phase 2 wave-parallel, no block barriers
// ---------------------------------------------------------------------------
__global__ __launch_bounds__(256) void k_final(
    const float* __restrict__ MH, const float* __restrict__ nodes,
    const float* __restrict__ mask, float* __restrict__ probs)
{
  __shared__ __align__(16) float lg[8*PROBN];     // 64 KB
  __shared__ __align__(16) float mh8[8*132];
  int tid = threadIdx.x;
  int b = blockIdx.x >> 5;
  int p0 = (blockIdx.x & 31) * 8;
  {
    int row = tid >> 5, c4 = (tid & 31) << 2;
    *(float4*)&mh8[row*132 + c4] = *(const float4*)&MH[(size_t)(b*POMO + p0 + row)*ED + c4];
  }
  __syncthreads();
  const float invs = 0.08838834764831845f;        // 1/sqrt(128)
  #pragma unroll
  for (int j = 0; j < 8; ++j) {
    int n = tid + (j << 8);
    const float4* nr = (const float4*)&nodes[(size_t)(b*PROBN + n)*ED];
    float a[8];
    #pragma unroll
    for (int p = 0; p < 8; ++p) a[p] = 0.f;
    float4 nv = nr[0];
    #pragma unroll 4
    for (int k4 = 0; k4 < 32; ++k4) {
      float4 cur = nv;
      if (k4 < 31) nv = nr[k4 + 1];
      #pragma unroll
      for (int p = 0; p < 8; ++p) {
        float4 mv = *(const float4*)&mh8[p*132 + (k4 << 2)];
        a[p] += mv.x*cur.x + mv.y*cur.y + mv.z*cur.z + mv.w*cur.w;
      }
    }
    #pragma unroll
    for (int p = 0; p < 8; ++p) lg[p*PROBN + n] = a[p] * invs;
  }
  __syncthreads();

  int wid = tid >> 6, lane = tid & 63;
  #pragma unroll
  for (int pp = 0; pp < 2; ++pp) {
    int p = wid*2 + pp;
    const float* mrow = mask + (size_t)(b*POMO + p0 + p) * PROBN;
    float* prow = probs + (size_t)(b*POMO + p0 + p) * PROBN;
    float z[32];
    float mx = -3.0e38f;
    #pragma unroll
    for (int i4 = 0; i4 < 8; ++i4) {
      int n = 4*lane + 256*i4;
      float4 lv = *(const float4*)&lg[p*PROBN + n];
      float4 mv = *(const float4*)&mrow[n];
      float z0 = 10.f - 20.f/(__expf(2.f*lv.x)+1.f) + mv.x;
      float z1 = 10.f - 20.f/(__expf(2.f*lv.y)+1.f) + mv.y;
      float z2 = 10.f - 20.f/(__expf(2.f*lv.z)+1.f) + mv.z;
      float z3 = 10.f - 20.f/(__expf(2.f*lv.w)+1.f) + mv.w;
      z[4*i4+0] = z0; z[4*i4+1] = z1; z[4*i4+2] = z2; z[4*i4+3] = z3;
      mx = fmaxf(fmaxf(fmaxf(mx, z0), fmaxf(z1, z2)), z3);
    }
    #pragma unroll
    for (int off = 32; off > 0; off >>= 1) mx = fmaxf(mx, __shfl_xor(mx, off));
    float sum = 0.f;
    #pragma unroll
    for (int k = 0; k < 32; ++k) { z[k] = __expf(z[k] - mx); sum += z[k]; }
    #pragma unroll
    for (int off = 32; off > 0; off >>= 1) sum += __shfl_xor(sum, off);
    float rs = 1.f / sum;
    #pragma unroll
    for (int i4 = 0; i4 < 8; ++i4) {
      int n = 4*lane + 256*i4;
      *(float4*)&prow[n] = make_float4(z[4*i4+0]*rs, z[4*i4+1]*rs,
                                       z[4*i4+2]*rs, z[4*i4+3]*rs);
    }
  }
}

// ---------------------------------------------------------------------------
extern "C" void kernel_launch(void* const* d_in, const int* in_sizes, int n_in,
                              void* d_out, int out_size, void* d_ws, size_t ws_size,
                              hipStream_t stream)
{
  const float* nodes  = (const float*)d_in[0];
  const float* last   = (const float*)d_in[1];
  const float* mid    = (const float*)d_in[2];
  const float* loadv  = (const float*)d_in[3];
  const float* mask   = (const float*)d_in[4];
  const float* Wq     = (const float*)d_in[5];
  const float* Wk     = (const float*)d_in[6];
  const float* Wv     = (const float*)d_in[7];
  const float* eW     = (const float*)d_in[8];
  const float* eB     = (const float*)d_in[9];
  const float* w_gate = (const float*)d_in[10];
  float* out = (float*)d_out;
  float* ws  = (float*)d_ws;

  k_gating<<<1, 128, 0, stream>>>(mid, w_gate, ws + WS_GATES, out + BB*POMO*PROBN);
  k_experts<<<16, 256, 0, stream>>>(ws + WS_GATES, eW, eB, ws + WS_WC, ws + WS_BC);
  k_kv<<<512, 256, 0, stream>>>(nodes, Wk, Wv, ws + WS_K, ws + WS_V);
  k_q<<<128, 256, 0, stream>>>(last, loadv, Wq, ws + WS_Q);
  k_attn<<<dim3(128, 8), 256, 0, stream>>>(ws + WS_K, ws + WS_V, ws + WS_Q, mask, ws + WS_OUT);
  k_mh<<<128, 256, 0, stream>>>(ws + WS_OUT, ws + WS_WC, ws + WS_BC, ws + WS_MH);
  k_final<<<512, 256, 0, stream>>>(ws + WS_MH, nodes, mask, out);
}

// Round 8
// 254.510 us; speedup vs baseline: 1.2743x; 1.2743x over previous
//
#include <hip/hip_runtime.h>
#include <math.h>

#define BB    16
#define PROBN 2048
#define POMO  256
#define ED    128
#define HN    8
#define DDIM  16
#define NEXP  8

// ws float offsets (total ~10.23M floats = ~40.9 MB)
#define WS_K     0
#define WS_V     (WS_K + BB*PROBN*ED)
#define WS_Q     (WS_V + BB*PROBN*ED)
#define WS_OUT   (WS_Q + BB*POMO*ED)
#define WS_MH    (WS_OUT + BB*POMO*ED)
#define WS_WC    (WS_MH + BB*POMO*ED)
#define WS_BC    (WS_WC + BB*ED*ED)
#define WS_GATES (WS_BC + BB*ED)

// ---------------------------------------------------------------------------
// K1: gating (top-2 softmax), gates -> ws, moe_loss -> d_out tail
// ---------------------------------------------------------------------------
__global__ __launch_bounds__(128) void k_gating(
    const float* __restrict__ mid, const float* __restrict__ w_gate,
    float* __restrict__ gates_ws, float* __restrict__ moe_out)
{
  __shared__ float lg[BB][NEXP];
  __shared__ float gt[BB][NEXP];
  int t = threadIdx.x;
  {
    int b = t >> 3, e = t & 7;
    float acc = 0.f;
    #pragma unroll 8
    for (int k = 0; k < ED; ++k) acc += mid[b*ED + k] * w_gate[k*NEXP + e];
    lg[b][e] = acc;
  }
  __syncthreads();
  if (t < BB) {
    int b = t;
    int i1 = 0; float v1 = lg[b][0];
    #pragma unroll
    for (int e = 1; e < NEXP; ++e) if (lg[b][e] > v1) { v1 = lg[b][e]; i1 = e; }
    int i2 = -1; float v2 = -3.0e38f;
    #pragma unroll
    for (int e = 0; e < NEXP; ++e) if (e != i1 && lg[b][e] > v2) { v2 = lg[b][e]; i2 = e; }
    float e2 = __expf(v2 - v1);          // <= 1
    float g1 = 1.f / (1.f + e2);
    #pragma unroll
    for (int e = 0; e < NEXP; ++e) gt[b][e] = 0.f;
    gt[b][i1] = g1;
    gt[b][i2] = e2 * g1;
  }
  __syncthreads();
  if (t < BB*NEXP) gates_ws[t] = gt[t >> 3][t & 7];
  if (t == 0) {
    float imp[NEXP], ldc[NEXP];
    #pragma unroll
    for (int e = 0; e < NEXP; ++e) { imp[e] = 0.f; ldc[e] = 0.f; }
    for (int b = 0; b < BB; ++b)
      #pragma unroll
      for (int e = 0; e < NEXP; ++e) {
        float g = gt[b][e];
        imp[e] += g;
        if (g > 0.f) ldc[e] += 1.f;
      }
    float im = 0.f, lm = 0.f;
    #pragma unroll
    for (int e = 0; e < NEXP; ++e) { im += imp[e]; lm += ldc[e]; }
    im *= 0.125f; lm *= 0.125f;
    float iv = 0.f, lv = 0.f;
    #pragma unroll
    for (int e = 0; e < NEXP; ++e) {
      float a = imp[e] - im; iv += a*a;
      float c = ldc[e] - lm; lv += c*c;
    }
    iv *= 0.125f; lv *= 0.125f;
    moe_out[0] = iv / (im*im + 1e-10f) + lv / (lm*lm + 1e-10f);
  }
}

// ---------------------------------------------------------------------------
// K2 v2: WC[b] = sum_e g_e * expert_W[e]; grid (b,tile) = 128 blocks
// (was grid=16: only 16 CUs active, HBM-latency-bound on 512KB/block streams)
// ---------------------------------------------------------------------------
__global__ __launch_bounds__(256) void k_experts(
    const float* __restrict__ gates, const float* __restrict__ eW,
    const float* __restrict__ eB, float* __restrict__ WC, float* __restrict__ BC)
{
  __shared__ float g[NEXP];
  int tid = threadIdx.x;
  int b = blockIdx.x >> 3;
  int tile = blockIdx.x & 7;           // 8 tiles of 2048 elements
  if (tid < NEXP) g[tid] = gates[b*NEXP + tid];
  __syncthreads();
  int i0 = tile * 2048;
  #pragma unroll
  for (int j = 0; j < 8; ++j) {
    int i = i0 + tid + j*256;
    float a = 0.f;
    #pragma unroll
    for (int e = 0; e < NEXP; ++e) a += g[e] * eW[e*ED*ED + i];
    WC[b*ED*ED + i] = a;
  }
  if (tile == 0 && tid < ED) {
    float a = 0.f;
    #pragma unroll
    for (int e = 0; e < NEXP; ++e) a += g[e] * eB[e*ED + tid];
    BC[b*ED + tid] = a;
  }
}

// ---------------------------------------------------------------------------
// K3: K = nodes@Wk, V = nodes@Wv   (32768x128 @ 128x128, x2, shared A tile)
// ---------------------------------------------------------------------------
__global__ __launch_bounds__(256) void k_kv(
    const float* __restrict__ nodes, const float* __restrict__ Wk,
    const float* __restrict__ Wv, float* __restrict__ Kp, float* __restrict__ Vp)
{
  __shared__ __align__(16) float As[64*132];
  __shared__ __align__(16) float Wks[32*128];
  __shared__ __align__(16) float Wvs[32*128];
  int tid = threadIdx.x;
  int r0 = blockIdx.x * 64;
  #pragma unroll
  for (int j = 0; j < 8; ++j) {
    int idx = tid + j*256;
    int row = idx >> 5, c4 = (idx & 31) << 2;
    *(float4*)&As[row*132 + c4] = *(const float4*)&nodes[(size_t)(r0 + row)*ED + c4];
  }
  int colg = tid & 15, rowg = tid >> 4;
  int c0 = colg << 2;              // cols c0..c0+3 and c0+64..c0+67
  float accK[4][8], accV[4][8];
  #pragma unroll
  for (int i = 0; i < 4; ++i)
    #pragma unroll
    for (int j = 0; j < 8; ++j) { accK[i][j] = 0.f; accV[i][j] = 0.f; }

  for (int kk = 0; kk < 128; kk += 32) {
    __syncthreads();
    #pragma unroll
    for (int j = 0; j < 4; ++j) {
      int idx = tid + j*256;
      int row = idx >> 5, c4 = (idx & 31) << 2;
      *(float4*)&Wks[row*128 + c4] = *(const float4*)&Wk[(kk + row)*ED + c4];
      *(float4*)&Wvs[row*128 + c4] = *(const float4*)&Wv[(kk + row)*ED + c4];
    }
    __syncthreads();
    #pragma unroll 4
    for (int k = 0; k < 32; ++k) {
      float a[4];
      #pragma unroll
      for (int i = 0; i < 4; ++i) a[i] = As[(rowg*4 + i)*132 + kk + k];
      float4 wk0 = *(float4*)&Wks[k*128 + c0];
      float4 wk1 = *(float4*)&Wks[k*128 + c0 + 64];
      float4 wv0 = *(float4*)&Wvs[k*128 + c0];
      float4 wv1 = *(float4*)&Wvs[k*128 + c0 + 64];
      #pragma unroll
      for (int i = 0; i < 4; ++i) {
        accK[i][0] += a[i]*wk0.x; accK[i][1] += a[i]*wk0.y;
        accK[i][2] += a[i]*wk0.z; accK[i][3] += a[i]*wk0.w;
        accK[i][4] += a[i]*wk1.x; accK[i][5] += a[i]*wk1.y;
        accK[i][6] += a[i]*wk1.z; accK[i][7] += a[i]*wk1.w;
        accV[i][0] += a[i]*wv0.x; accV[i][1] += a[i]*wv0.y;
        accV[i][2] += a[i]*wv0.z; accV[i][3] += a[i]*wv0.w;
        accV[i][4] += a[i]*wv1.x; accV[i][5] += a[i]*wv1.y;
        accV[i][6] += a[i]*wv1.z; accV[i][7] += a[i]*wv1.w;
      }
    }
  }
  #pragma unroll
  for (int i = 0; i < 4; ++i) {
    size_t row = (size_t)(r0 + rowg*4 + i) * ED;
    *(float4*)&Kp[row + c0]      = make_float4(accK[i][0], accK[i][1], accK[i][2], accK[i][3]);
    *(float4*)&Kp[row + c0 + 64] = make_float4(accK[i][4], accK[i][5], accK[i][6], accK[i][7]);
    *(float4*)&Vp[row + c0]      = make_float4(accV[i][0], accV[i][1], accV[i][2], accV[i][3]);
    *(float4*)&Vp[row + c0 + 64] = make_float4(accV[i][4], accV[i][5], accV[i][6], accV[i][7]);
  }
}

// ---------------------------------------------------------------------------
// K4: Q = [last, load] @ Wq_last   (4096x129 @ 129x128)
// ---------------------------------------------------------------------------
__global__ __launch_bounds__(256) void k_q(
    const float* __restrict__ last, const float* __restrict__ loadv,
    const float* __restrict__ Wq, float* __restrict__ Qp)
{
  __shared__ __align__(16) float As[32*132];
  __shared__ __align__(16) float Ws[129*128];
  int tid = threadIdx.x;
  int r0 = blockIdx.x * 32;
  #pragma unroll
  for (int j = 0; j < 4; ++j) {
    int idx = tid + j*256;
    int row = idx >> 5, c4 = (idx & 31) << 2;
    *(float4*)&As[row*132 + c4] = *(const float4*)&last[(size_t)(r0 + row)*ED + c4];
  }
  if (tid < 32) As[tid*132 + 128] = loadv[r0 + tid];
  for (int idx = tid; idx < 4128; idx += 256)
    *(float4*)&Ws[idx*4] = *(const float4*)&Wq[idx*4];
  __syncthreads();

  int colg = tid & 15, rowg = tid >> 4;
  int c0 = colg << 2;
  float acc[2][8];
  #pragma unroll
  for (int i = 0; i < 2; ++i)
    #pragma unroll
    for (int j = 0; j < 8; ++j) acc[i][j] = 0.f;
  #pragma unroll 4
  for (int k = 0; k < 129; ++k) {
    float a0 = As[(rowg*2)*132 + k];
    float a1 = As[(rowg*2 + 1)*132 + k];
    float4 w0 = *(float4*)&Ws[k*128 + c0];
    float4 w1 = *(float4*)&Ws[k*128 + c0 + 64];
    acc[0][0] += a0*w0.x; acc[0][1] += a0*w0.y; acc[0][2] += a0*w0.z; acc[0][3] += a0*w0.w;
    acc[0][4] += a0*w1.x; acc[0][5] += a0*w1.y; acc[0][6] += a0*w1.z; acc[0][7] += a0*w1.w;
    acc[1][0] += a1*w0.x; acc[1][1] += a1*w0.y; acc[1][2] += a1*w0.z; acc[1][3] += a1*w0.w;
    acc[1][4] += a1*w1.x; acc[1][5] += a1*w1.y; acc[1][6] += a1*w1.z; acc[1][7] += a1*w1.w;
  }
  #pragma unroll
  for (int i = 0; i < 2; ++i) {
    size_t row = (size_t)(r0 + rowg*2 + i) * ED;
    *(float4*)&Qp[row + c0]      = make_float4(acc[i][0], acc[i][1], acc[i][2], acc[i][3]);
    *(float4*)&Qp[row + c0 + 64] = make_float4(acc[i][4], acc[i][5], acc[i][6], acc[i][7]);
  }
}

// ---------------------------------------------------------------------------
// K5 = R3/R6 proven version (112 µs, VGPR 64, no scratch). FROZEN.
// Four failed attempts to restructure (R2 4q/thread, R4 prefetch+(256,3),
// R5 quad-map+defer-max, R7 KVBLK=256) all spilled acc -> GB-scale scratch.
// Guard: WRITE_SIZE must stay KB-scale.
// ---------------------------------------------------------------------------
__global__ __launch_bounds__(256, 4) void k_attn(
    const float* __restrict__ Kp, const float* __restrict__ Vp,
    const float* __restrict__ Qp, const float* __restrict__ mask,
    float* __restrict__ Op)
{
  __shared__ __align__(16) float kt[128*20];
  __shared__ __align__(16) float vt[128*20];
  int tid = threadIdx.x;
  int h = blockIdx.x & 7, b = blockIdx.x >> 3;
  int ph = blockIdx.y;
  int nq = tid & 15;          // 16 stripes, rows nq + 16*i
  int pg = tid >> 4;          // 16 groups x 2 queries = 32 q/block
  int prow0 = b*POMO + ph*32 + pg*2;
  const float* maskb = mask + (size_t)prow0 * PROBN;
  const float* Kb = Kp + (size_t)b*PROBN*ED + h*16;
  const float* Vb = Vp + (size_t)b*PROBN*ED + h*16;

  float q[2][16];
  #pragma unroll
  for (int qi = 0; qi < 2; ++qi)
    #pragma unroll
    for (int d4 = 0; d4 < 4; ++d4) {
      float4 t = *(const float4*)&Qp[(size_t)(prow0 + qi)*ED + h*16 + d4*4];
      q[qi][4*d4+0] = t.x; q[qi][4*d4+1] = t.y; q[qi][4*d4+2] = t.z; q[qi][4*d4+3] = t.w;
    }
  float m[2], l[2], acc[2][16];
  #pragma unroll
  for (int qi = 0; qi < 2; ++qi) {
    m[qi] = -1.0e30f; l[qi] = 0.f;
    #pragma unroll
    for (int dd = 0; dd < 16; ++dd) acc[qi][dd] = 0.f;
  }

  // staging geometry: idx = tid + j*256 -> row = idx>>2, d4 = (idx&3)<<2
  // column XOR'd with row bit3 (matches read-side sw) -> conflict-free
  int srow0 = tid >> 2, sd4 = (tid & 3) << 2;
  int sp0 = sd4 ^ (((srow0 >> 3) & 1) << 2);
  int srow1 = srow0 + 64;
  int sp1 = sd4 ^ (((srow1 >> 3) & 1) << 2);
  int sw = ((nq >> 3) & 1) << 2;

  for (int tile = 0; tile < 16; ++tile) {
    int t0 = tile << 7;
    if (tile > 0) __syncthreads();     // previous tile fully consumed
    // ---- stage K/V tile (one coalesced batch; other blocks hide the wait) --
    *(float4*)&kt[srow0*20 + sp0] = *(const float4*)&Kb[(size_t)(t0 + srow0)*ED + sd4];
    *(float4*)&vt[srow0*20 + sp0] = *(const float4*)&Vb[(size_t)(t0 + srow0)*ED + sd4];
    *(float4*)&kt[srow1*20 + sp1] = *(const float4*)&Kb[(size_t)(t0 + srow1)*ED + sd4];
    *(float4*)&vt[srow1*20 + sp1] = *(const float4*)&Vb[(size_t)(t0 + srow1)*ED + sd4];
    __syncthreads();

    // ---- scores: s[q][i] = q . K[nq+16i] * 0.25 + mask ----
    float s[2][8];
    #pragma unroll
    for (int qi = 0; qi < 2; ++qi)
      #pragma unroll
      for (int i = 0; i < 8; ++i)
        s[qi][i] = maskb[(size_t)qi*PROBN + t0 + nq + 16*i];
    #pragma unroll
    for (int i = 0; i < 8; ++i) {
      int nl = nq + 16*i;
      float kr[16];
      #pragma unroll
      for (int D4 = 0; D4 < 4; ++D4) {
        float4 kv = *(float4*)&kt[nl*20 + ((D4 << 2) ^ sw)];
        kr[4*D4+0] = kv.x; kr[4*D4+1] = kv.y; kr[4*D4+2] = kv.z; kr[4*D4+3] = kv.w;
      }
      #pragma unroll
      for (int qi = 0; qi < 2; ++qi) {
        float d = 0.f;
        #pragma unroll
        for (int dd = 0; dd < 16; ++dd) d += q[qi][dd] * kr[dd];
        s[qi][i] += d * 0.25f;
      }
    }
    // ---- per-tile max merge + single rescale ----
    #pragma unroll
    for (int qi = 0; qi < 2; ++qi) {
      float tm = s[qi][0];
      #pragma unroll
      for (int i = 1; i < 8; ++i) tm = fmaxf(tm, s[qi][i]);
      float M = fmaxf(m[qi], tm);
      float c = __expf(m[qi] - M);
      m[qi] = M;
      l[qi] *= c;
      #pragma unroll
      for (int dd = 0; dd < 16; ++dd) acc[qi][dd] *= c;
    }
    // ---- exp + PV accumulate ----
    #pragma unroll
    for (int i = 0; i < 8; ++i) {
      int nl = nq + 16*i;
      float vr[16];
      #pragma unroll
      for (int D4 = 0; D4 < 4; ++D4) {
        float4 vv = *(float4*)&vt[nl*20 + ((D4 << 2) ^ sw)];
        vr[4*D4+0] = vv.x; vr[4*D4+1] = vv.y; vr[4*D4+2] = vv.z; vr[4*D4+3] = vv.w;
      }
      #pragma unroll
      for (int qi = 0; qi < 2; ++qi) {
        float w = __expf(s[qi][i] - m[qi]);
        l[qi] += w;
        #pragma unroll
        for (int dd = 0; dd < 16; ++dd) acc[qi][dd] += w * vr[dd];
      }
    }
  }

  // merge 16 stripes (tid bits 0..3, within wave)
  #pragma unroll
  for (int off = 1; off < 16; off <<= 1) {
    #pragma unroll
    for (int qi = 0; qi < 2; ++qi) {
      float m2 = __shfl_xor(m[qi], off);
      float l2 = __shfl_xor(l[qi], off);
      float M = fmaxf(m[qi], m2);
      float c1 = __expf(m[qi] - M), c2 = __expf(m2 - M);
      l[qi] = l[qi]*c1 + l2*c2;
      m[qi] = M;
      #pragma unroll
      for (int dd = 0; dd < 16; ++dd) {
        float a2 = __shfl_xor(acc[qi][dd], off);
        acc[qi][dd] = acc[qi][dd]*c1 + a2*c2;
      }
    }
  }
  // write: lanes nq<4, compile-time indexed via unrolled-if (rule #20)
  #pragma unroll
  for (int d4 = 0; d4 < 4; ++d4) {
    if (nq == d4) {
      #pragma unroll
      for (int qi = 0; qi < 2; ++qi) {
        float rl = 1.f / l[qi];
        *(float4*)&Op[(size_t)(prow0 + qi)*ED + h*16 + d4*4] =
          make_float4(acc[qi][4*d4+0]*rl, acc[qi][4*d4+1]*rl,
                      acc[qi][4*d4+2]*rl, acc[qi][4*d4+3]*rl);
      }
    }
  }
}

// ---------------------------------------------------------------------------
// K6: MH = OUT @ WC[b] + BC[b]   (per-batch 256x128 @ 128x128)
// ---------------------------------------------------------------------------
__global__ __launch_bounds__(256) void k_mh(
    const float* __restrict__ Op, const float* __restrict__ WC,
    const float* __restrict__ BC, float* __restrict__ MH)
{
  __shared__ __align__(16) float As[32*132];
  __shared__ __align__(16) float Ws[128*128];
  int tid = threadIdx.x;
  int b = blockIdx.x >> 3;
  int pt = blockIdx.x & 7;
  int r0 = b*POMO + pt*32;
  #pragma unroll
  for (int j = 0; j < 4; ++j) {
    int idx = tid + j*256;
    int row = idx >> 5, c4 = (idx & 31) << 2;
    *(float4*)&As[row*132 + c4] = *(const float4*)&Op[(size_t)(r0 + row)*ED + c4];
  }
  for (int idx = tid; idx < 4096; idx += 256)
    *(float4*)&Ws[idx*4] = *(const float4*)&WC[(size_t)b*ED*ED + idx*4];
  __syncthreads();

  int colg = tid & 15, rowg = tid >> 4;
  int c0 = colg << 2;
  float4 b0 = *(const float4*)&BC[b*ED + c0];
  float4 b1 = *(const float4*)&BC[b*ED + c0 + 64];
  float acc[2][8];
  #pragma unroll
  for (int i = 0; i < 2; ++i) {
    acc[i][0] = b0.x; acc[i][1] = b0.y; acc[i][2] = b0.z; acc[i][3] = b0.w;
    acc[i][4] = b1.x; acc[i][5] = b1.y; acc[i][6] = b1.z; acc[i][7] = b1.w;
  }
  #pragma unroll 4
  for (int k = 0; k < 128; ++k) {
    float a0 = As[(rowg*2)*132 + k];
    float a1 = As[(rowg*2 + 1)*132 + k];
    float4 w0 = *(float4*)&Ws[k*128 + c0];
    float4 w1 = *(float4*)&Ws[k*128 + c0 + 64];
    acc[0][0] += a0*w0.x; acc[0][1] += a0*w0.y; acc[0][2] += a0*w0.z; acc[0][3] += a0*w0.w;
    acc[0][4] += a0*w1.x; acc[0][5] += a0*w1.y; acc[0][6] += a0*w1.z; acc[0][7] += a0*w1.w;
    acc[1][0] += a1*w0.x; acc[1][1] += a1*w0.y; acc[1][2] += a1*w0.z; acc[1][3] += a1*w0.w;
    acc[1][4] += a1*w1.x; acc[1][5] += a1*w1.y; acc[1][6] += a1*w1.z; acc[1][7] += a1*w1.w;
  }
  #pragma unroll
  for (int i = 0; i < 2; ++i) {
    size_t row = (size_t)(r0 + rowg*2 + i) * ED;
    *(float4*)&MH[row + c0]      = make_float4(acc[i][0], acc[i][1], acc[i][2], acc[i][3]);
    *(float4*)&MH[row + c0 + 64] = make_float4(acc[i][4], acc[i][5], acc[i][6], acc[i][7]);
  }
}

// ---------------------------------------------------------------------------
// K7 v2: score2 = MH @ nodes^T / sqrt(E); probs = softmax(10*tanh + mask)
// phase 1: logits [8][2048] into LDS; phase 2 wave-parallel, no block barriers
// ---------------------------------------------------------------------------
__global__ __launch_bounds__(256) void k_final(
    const float* __restrict__ MH, const float* __restrict__ nodes,
    const float* __restrict__ mask, float* __restrict__ probs)
{
  __shared__ __align__(16) float lg[8*PROBN];     // 64 KB
  __shared__ __align__(16) float mh8[8*132];
  int tid = threadIdx.x;
  int b = blockIdx.x >> 5;
  int p0 = (blockIdx.x & 31) * 8;
  {
    int row = tid >> 5, c4 = (tid & 31) << 2;
    *(float4*)&mh8[row*132 + c4] = *(const float4*)&MH[(size_t)(b*POMO + p0 + row)*ED + c4];
  }
  __syncthreads();
  const float invs = 0.08838834764831845f;        // 1/sqrt(128)
  #pragma unroll
  for (int j = 0; j < 8; ++j) {
    int n = tid + (j << 8);
    const float4* nr = (const float4*)&nodes[(size_t)(b*PROBN + n)*ED];
    float a[8];
    #pragma unroll
    for (int p = 0; p < 8; ++p) a[p] = 0.f;
    float4 nv = nr[0];
    #pragma unroll 4
    for (int k4 = 0; k4 < 32; ++k4) {
      float4 cur = nv;
      if (k4 < 31) nv = nr[k4 + 1];
      #pragma unroll
      for (int p = 0; p < 8; ++p) {
        float4 mv = *(const float4*)&mh8[p*132 + (k4 << 2)];
        a[p] += mv.x*cur.x + mv.y*cur.y + mv.z*cur.z + mv.w*cur.w;
      }
    }
    #pragma unroll
    for (int p = 0; p < 8; ++p) lg[p*PROBN + n] = a[p] * invs;
  }
  __syncthreads();

  int wid = tid >> 6, lane = tid & 63;
  #pragma unroll
  for (int pp = 0; pp < 2; ++pp) {
    int p = wid*2 + pp;
    const float* mrow = mask + (size_t)(b*POMO + p0 + p) * PROBN;
    float* prow = probs + (size_t)(b*POMO + p0 + p) * PROBN;
    float z[32];
    float mx = -3.0e38f;
    #pragma unroll
    for (int i4 = 0; i4 < 8; ++i4) {
      int n = 4*lane + 256*i4;
      float4 lv = *(const float4*)&lg[p*PROBN + n];
      float4 mv = *(const float4*)&mrow[n];
      float z0 = 10.f - 20.f/(__expf(2.f*lv.x)+1.f) + mv.x;
      float z1 = 10.f - 20.f/(__expf(2.f*lv.y)+1.f) + mv.y;
      float z2 = 10.f - 20.f/(__expf(2.f*lv.z)+1.f) + mv.z;
      float z3 = 10.f - 20.f/(__expf(2.f*lv.w)+1.f) + mv.w;
      z[4*i4+0] = z0; z[4*i4+1] = z1; z[4*i4+2] = z2; z[4*i4+3] = z3;
      mx = fmaxf(fmaxf(fmaxf(mx, z0), fmaxf(z1, z2)), z3);
    }
    #pragma unroll
    for (int off = 32; off > 0; off >>= 1) mx = fmaxf(mx, __shfl_xor(mx, off));
    float sum = 0.f;
    #pragma unroll
    for (int k = 0; k < 32; ++k) { z[k] = __expf(z[k] - mx); sum += z[k]; }
    #pragma unroll
    for (int off = 32; off > 0; off >>= 1) sum += __shfl_xor(sum, off);
    float rs = 1.f / sum;
    #pragma unroll
    for (int i4 = 0; i4 < 8; ++i4) {
      int n = 4*lane + 256*i4;
      *(float4*)&prow[n] = make_float4(z[4*i4+0]*rs, z[4*i4+1]*rs,
                                       z[4*i4+2]*rs, z[4*i4+3]*rs);
    }
  }
}

// ---------------------------------------------------------------------------
extern "C" void kernel_launch(void* const* d_in, const int* in_sizes, int n_in,
                              void* d_out, int out_size, void* d_ws, size_t ws_size,
                              hipStream_t stream)
{
  const float* nodes  = (const float*)d_in[0];
  const float* last   = (const float*)d_in[1];
  const float* mid    = (const float*)d_in[2];
  const float* loadv  = (const float*)d_in[3];
  const float* mask   = (const float*)d_in[4];
  const float* Wq     = (const float*)d_in[5];
  const float* Wk     = (const float*)d_in[6];
  const float* Wv     = (const float*)d_in[7];
  const float* eW     = (const float*)d_in[8];
  const float* eB     = (const float*)d_in[9];
  const float* w_gate = (const float*)d_in[10];
  float* out = (float*)d_out;
  float* ws  = (float*)d_ws;

  k_gating<<<1, 128, 0, stream>>>(mid, w_gate, ws + WS_GATES, out + BB*POMO*PROBN);
  k_experts<<<128, 256, 0, stream>>>(ws + WS_GATES, eW, eB, ws + WS_WC, ws + WS_BC);
  k_kv<<<512, 256, 0, stream>>>(nodes, Wk, Wv, ws + WS_K, ws + WS_V);
  k_q<<<128, 256, 0, stream>>>(last, loadv, Wq, ws + WS_Q);
  k_attn<<<dim3(128, 8), 256, 0, stream>>>(ws + WS_K, ws + WS_V, ws + WS_Q, mask, ws + WS_OUT);
  k_mh<<<128, 256, 0, stream>>>(ws + WS_OUT, ws + WS_WC, ws + WS_BC, ws + WS_MH);
  k_final<<<512, 256, 0, stream>>>(ws + WS_MH, nodes, mask, out);
}

// Round 9
// 192.665 us; speedup vs baseline: 1.6834x; 1.3210x over previous
//
#include <hip/hip_runtime.h>
#include <math.h>

#define BB    16
#define PROBN 2048
#define POMO  256
#define ED    128
#define HN    8
#define DDIM  16
#define NEXP  8

typedef _Float16 f16;
typedef f16 f16x2 __attribute__((ext_vector_type(2)));

__device__ __forceinline__ f16x2 f2h(float f) {
  union U { float f; f16x2 h; } u; u.f = f; return u.h;
}
__device__ __forceinline__ float packh2(float a, float b) {
  union U { float f; f16x2 h; } u; u.h.x = (f16)a; u.h.y = (f16)b; return u.f;
}
__device__ __forceinline__ float fdot2f(f16x2 a, f16x2 b, float c) {
#if __has_builtin(__builtin_amdgcn_fdot2)
  return __builtin_amdgcn_fdot2(a, b, c, false);
#else
  return c + (float)a.x * (float)b.x + (float)a.y * (float)b.y;
#endif
}

// ws float offsets (f16 arrays addressed as float*; total ~7.87M floats = 31.5MB)
#define WS_KH    0                        // f16 K [b][n][h*16+d]   (2,097,152 floats)
#define WS_VHT   (WS_KH + 2097152)        // f16 V^T [b][h*16+d][n] (2,097,152)
#define WS_NH    (WS_VHT + 2097152)       // f16 nodes [b][n][d]    (2,097,152)
#define WS_QH    (WS_NH + 2097152)        // f16 Q [b*POMO][d]      (262,144)
#define WS_OUT   (WS_QH + 262144)         // fp32 attn out          (524,288)
#define WS_MH    (WS_OUT + 524288)        // fp32 MoE out           (524,288)
#define WS_WC    (WS_MH + 524288)         // fp32 combined expert W (262,144)
#define WS_BC    (WS_WC + 262144)         // fp32 combined bias     (2,048)
#define WS_GATES (WS_BC + 2048)

// ---------------------------------------------------------------------------
// K1: gating (top-2 softmax), gates -> ws, moe_loss -> d_out tail.
// STAYS FP32-EXACT: moe_loss is the only strictly-checked output (thr 1.39e-2).
// ---------------------------------------------------------------------------
__global__ __launch_bounds__(128) void k_gating(
    const float* __restrict__ mid, const float* __restrict__ w_gate,
    float* __restrict__ gates_ws, float* __restrict__ moe_out)
{
  __shared__ float lg[BB][NEXP];
  __shared__ float gt[BB][NEXP];
  int t = threadIdx.x;
  {
    int b = t >> 3, e = t & 7;
    float acc = 0.f;
    #pragma unroll 8
    for (int k = 0; k < ED; ++k) acc += mid[b*ED + k] * w_gate[k*NEXP + e];
    lg[b][e] = acc;
  }
  __syncthreads();
  if (t < BB) {
    int b = t;
    int i1 = 0; float v1 = lg[b][0];
    #pragma unroll
    for (int e = 1; e < NEXP; ++e) if (lg[b][e] > v1) { v1 = lg[b][e]; i1 = e; }
    int i2 = -1; float v2 = -3.0e38f;
    #pragma unroll
    for (int e = 0; e < NEXP; ++e) if (e != i1 && lg[b][e] > v2) { v2 = lg[b][e]; i2 = e; }
    float e2 = __expf(v2 - v1);          // <= 1
    float g1 = 1.f / (1.f + e2);
    #pragma unroll
    for (int e = 0; e < NEXP; ++e) gt[b][e] = 0.f;
    gt[b][i1] = g1;
    gt[b][i2] = e2 * g1;
  }
  __syncthreads();
  if (t < BB*NEXP) gates_ws[t] = gt[t >> 3][t & 7];
  if (t == 0) {
    float imp[NEXP], ldc[NEXP];
    #pragma unroll
    for (int e = 0; e < NEXP; ++e) { imp[e] = 0.f; ldc[e] = 0.f; }
    for (int b = 0; b < BB; ++b)
      #pragma unroll
      for (int e = 0; e < NEXP; ++e) {
        float g = gt[b][e];
        imp[e] += g;
        if (g > 0.f) ldc[e] += 1.f;
      }
    float im = 0.f, lm = 0.f;
    #pragma unroll
    for (int e = 0; e < NEXP; ++e) { im += imp[e]; lm += ldc[e]; }
    im *= 0.125f; lm *= 0.125f;
    float iv = 0.f, lv = 0.f;
    #pragma unroll
    for (int e = 0; e < NEXP; ++e) {
      float a = imp[e] - im; iv += a*a;
      float c = ldc[e] - lm; lv += c*c;
    }
    iv *= 0.125f; lv *= 0.125f;
    moe_out[0] = iv / (im*im + 1e-10f) + lv / (lm*lm + 1e-10f);
  }
}

// ---------------------------------------------------------------------------
// K2: WC[b] = sum_e g_e * expert_W[e]; grid (b,tile) = 128 blocks (R8 proven)
// ---------------------------------------------------------------------------
__global__ __launch_bounds__(256) void k_experts(
    const float* __restrict__ gates, const float* __restrict__ eW,
    const float* __restrict__ eB, float* __restrict__ WC, float* __restrict__ BC)
{
  __shared__ float g[NEXP];
  int tid = threadIdx.x;
  int b = blockIdx.x >> 3;
  int tile = blockIdx.x & 7;           // 8 tiles of 2048 elements
  if (tid < NEXP) g[tid] = gates[b*NEXP + tid];
  __syncthreads();
  int i0 = tile * 2048;
  #pragma unroll
  for (int j = 0; j < 8; ++j) {
    int i = i0 + tid + j*256;
    float a = 0.f;
    #pragma unroll
    for (int e = 0; e < NEXP; ++e) a += g[e] * eW[e*ED*ED + i];
    WC[b*ED*ED + i] = a;
  }
  if (tile == 0 && tid < ED) {
    float a = 0.f;
    #pragma unroll
    for (int e = 0; e < NEXP; ++e) a += g[e] * eB[e*ED + tid];
    BC[b*ED + tid] = a;
  }
}

// ---------------------------------------------------------------------------
// K3 v3: fp32 GEMM compute (unchanged core), f16 outputs:
//   Khf = K row-major f16, VhTf = V transposed f16 [b][h*16+d][n],
//   Nhf = nodes f16 copy (for k_final fdot2 path).
// ---------------------------------------------------------------------------
__global__ __launch_bounds__(256) void k_kv(
    const float* __restrict__ nodes, const float* __restrict__ Wk,
    const float* __restrict__ Wv, float* __restrict__ Khf,
    float* __restrict__ VhTf, float* __restrict__ Nhf)
{
  __shared__ __align__(16) float As[64*132];
  __shared__ __align__(16) float Wks[32*128];
  __shared__ __align__(16) float Wvs[32*128];
  int tid = threadIdx.x;
  int r0 = blockIdx.x * 64;
  #pragma unroll
  for (int j = 0; j < 8; ++j) {
    int idx = tid + j*256;
    int row = idx >> 5, c4 = (idx & 31) << 2;
    float4 v = *(const float4*)&nodes[(size_t)(r0 + row)*ED + c4];
    *(float4*)&As[row*132 + c4] = v;
    float2 nh; nh.x = packh2(v.x, v.y); nh.y = packh2(v.z, v.w);
    *(float2*)&Nhf[(size_t)(r0 + row)*64 + (c4 >> 1)] = nh;
  }
  int colg = tid & 15, rowg = tid >> 4;
  int c0 = colg << 2;              // cols c0..c0+3 and c0+64..c0+67
  float accK[4][8], accV[4][8];
  #pragma unroll
  for (int i = 0; i < 4; ++i)
    #pragma unroll
    for (int j = 0; j < 8; ++j) { accK[i][j] = 0.f; accV[i][j] = 0.f; }

  for (int kk = 0; kk < 128; kk += 32) {
    __syncthreads();
    #pragma unroll
    for (int j = 0; j < 4; ++j) {
      int idx = tid + j*256;
      int row = idx >> 5, c4 = (idx & 31) << 2;
      *(float4*)&Wks[row*128 + c4] = *(const float4*)&Wk[(kk + row)*ED + c4];
      *(float4*)&Wvs[row*128 + c4] = *(const float4*)&Wv[(kk + row)*ED + c4];
    }
    __syncthreads();
    #pragma unroll 4
    for (int k = 0; k < 32; ++k) {
      float a[4];
      #pragma unroll
      for (int i = 0; i < 4; ++i) a[i] = As[(rowg*4 + i)*132 + kk + k];
      float4 wk0 = *(float4*)&Wks[k*128 + c0];
      float4 wk1 = *(float4*)&Wks[k*128 + c0 + 64];
      float4 wv0 = *(float4*)&Wvs[k*128 + c0];
      float4 wv1 = *(float4*)&Wvs[k*128 + c0 + 64];
      #pragma unroll
      for (int i = 0; i < 4; ++i) {
        accK[i][0] += a[i]*wk0.x; accK[i][1] += a[i]*wk0.y;
        accK[i][2] += a[i]*wk0.z; accK[i][3] += a[i]*wk0.w;
        accK[i][4] += a[i]*wk1.x; accK[i][5] += a[i]*wk1.y;
        accK[i][6] += a[i]*wk1.z; accK[i][7] += a[i]*wk1.w;
        accV[i][0] += a[i]*wv0.x; accV[i][1] += a[i]*wv0.y;
        accV[i][2] += a[i]*wv0.z; accV[i][3] += a[i]*wv0.w;
        accV[i][4] += a[i]*wv1.x; accV[i][5] += a[i]*wv1.y;
        accV[i][6] += a[i]*wv1.z; accV[i][7] += a[i]*wv1.w;
      }
    }
  }
  // K: f16 row-major
  #pragma unroll
  for (int i = 0; i < 4; ++i) {
    size_t row = (size_t)(r0 + rowg*4 + i);
    float2 k0; k0.x = packh2(accK[i][0], accK[i][1]); k0.y = packh2(accK[i][2], accK[i][3]);
    float2 k1; k1.x = packh2(accK[i][4], accK[i][5]); k1.y = packh2(accK[i][6], accK[i][7]);
    *(float2*)&Khf[row*64 + (c0 >> 1)]      = k0;
    *(float2*)&Khf[row*64 + (c0 >> 1) + 32] = k1;
  }
  // V: f16 transposed [b][col][n] — thread's 4 rows are consecutive n
  int bb = r0 >> 11;
  int nn0 = (r0 & 2047) + rowg*4;
  #pragma unroll
  for (int j = 0; j < 8; ++j) {
    int col = (j < 4) ? (c0 + j) : (c0 + 60 + j);
    float2 vv; vv.x = packh2(accV[0][j], accV[1][j]); vv.y = packh2(accV[2][j], accV[3][j]);
    *(float2*)&VhTf[((size_t)bb*128 + col)*1024 + (nn0 >> 1)] = vv;
  }
}

// ---------------------------------------------------------------------------
// K4 v2: Q = [last, load] @ Wq_last, f16 output
// ---------------------------------------------------------------------------
__global__ __launch_bounds__(256) void k_q(
    const float* __restrict__ last, const float* __restrict__ loadv,
    const float* __restrict__ Wq, float* __restrict__ Qhf)
{
  __shared__ __align__(16) float As[32*132];
  __shared__ __align__(16) float Ws[129*128];
  int tid = threadIdx.x;
  int r0 = blockIdx.x * 32;
  #pragma unroll
  for (int j = 0; j < 4; ++j) {
    int idx = tid + j*256;
    int row = idx >> 5, c4 = (idx & 31) << 2;
    *(float4*)&As[row*132 + c4] = *(const float4*)&last[(size_t)(r0 + row)*ED + c4];
  }
  if (tid < 32) As[tid*132 + 128] = loadv[r0 + tid];
  for (int idx = tid; idx < 4128; idx += 256)
    *(float4*)&Ws[idx*4] = *(const float4*)&Wq[idx*4];
  __syncthreads();

  int colg = tid & 15, rowg = tid >> 4;
  int c0 = colg << 2;
  float acc[2][8];
  #pragma unroll
  for (int i = 0; i < 2; ++i)
    #pragma unroll
    for (int j = 0; j < 8; ++j) acc[i][j] = 0.f;
  #pragma unroll 4
  for (int k = 0; k < 129; ++k) {
    float a0 = As[(rowg*2)*132 + k];
    float a1 = As[(rowg*2 + 1)*132 + k];
    float4 w0 = *(float4*)&Ws[k*128 + c0];
    float4 w1 = *(float4*)&Ws[k*128 + c0 + 64];
    acc[0][0] += a0*w0.x; acc[0][1] += a0*w0.y; acc[0][2] += a0*w0.z; acc[0][3] += a0*w0.w;
    acc[0][4] += a0*w1.x; acc[0][5] += a0*w1.y; acc[0][6] += a0*w1.z; acc[0][7] += a0*w1.w;
    acc[1][0] += a1*w0.x; acc[1][1] += a1*w0.y; acc[1][2] += a1*w0.z; acc[1][3] += a1*w0.w;
    acc[1][4] += a1*w1.x; acc[1][5] += a1*w1.y; acc[1][6] += a1*w1.z; acc[1][7] += a1*w1.w;
  }
  #pragma unroll
  for (int i = 0; i < 2; ++i) {
    size_t row = (size_t)(r0 + rowg*2 + i);
    float2 q0; q0.x = packh2(acc[i][0], acc[i][1]); q0.y = packh2(acc[i][2], acc[i][3]);
    float2 q1; q1.x = packh2(acc[i][4], acc[i][5]); q1.y = packh2(acc[i][6], acc[i][7]);
    *(float2*)&Qhf[row*64 + (c0 >> 1)]      = q0;
    *(float2*)&Qhf[row*64 + (c0 >> 1) + 32] = q1;
  }
}

// ---------------------------------------------------------------------------
// K5 v7: flash attention, f16 inputs + v_dot2_f32_f16, FP32 accumulators.
// R6 skeleton preserved: grid (128,8), 2q/thread, 16 stripes, unconditional
// per-tile rescale, direct global->LDS staging, (256,4). Thread owns key
// PAIRS {2nq+32i, +1}: scores 8 fdot2/key; PV acc[dd]=fdot2((w0,w1),VT,acc).
// DO NOT add: reg prefetch, vectorized mask map, defer-max (R2/R4/R5/R7).
// Guard: WRITE_SIZE must stay KB-scale.
// ---------------------------------------------------------------------------
__global__ __launch_bounds__(256, 4) void k_attn(
    const float* __restrict__ Khf, const float* __restrict__ VhTf,
    const float* __restrict__ Qhf, const float* __restrict__ mask,
    float* __restrict__ Op)
{
  __shared__ __align__(16) float kt[64*20];   // 64 key-pairs x (32 halfs + pad)
  __shared__ __align__(16) float vt[16*68];   // 16 d-rows x (128 key halfs + pad)
  int tid = threadIdx.x;
  int h = blockIdx.x & 7, b = blockIdx.x >> 3;
  int ph = blockIdx.y;
  int nq = tid & 15;
  int pg = tid >> 4;
  int prow0 = b*POMO + ph*32 + pg*2;
  const float* maskb = mask + (size_t)prow0 * PROBN;
  const float* Kb = Khf + (size_t)b*PROBN*64 + h*8;        // float units
  const float* Vb = VhTf + ((size_t)b*128 + h*16)*1024;    // d-row stride 1024 floats

  f16x2 q[2][8];
  #pragma unroll
  for (int qi = 0; qi < 2; ++qi) {
    const float* qp = Qhf + (size_t)(prow0 + qi)*64 + h*8;
    float4 t0 = *(const float4*)&qp[0];
    float4 t1 = *(const float4*)&qp[4];
    q[qi][0] = f2h(t0.x); q[qi][1] = f2h(t0.y); q[qi][2] = f2h(t0.z); q[qi][3] = f2h(t0.w);
    q[qi][4] = f2h(t1.x); q[qi][5] = f2h(t1.y); q[qi][6] = f2h(t1.z); q[qi][7] = f2h(t1.w);
  }
  float m[2], l[2], acc[2][16];
  #pragma unroll
  for (int qi = 0; qi < 2; ++qi) {
    m[qi] = -1.0e30f; l[qi] = 0.f;
    #pragma unroll
    for (int dd = 0; dd < 16; ++dd) acc[qi][dd] = 0.f;
  }

  int srow = tid >> 1, part = tid & 1;                  // K staging: 2 thr/row
  int kws = 20*(srow >> 1) + 8*(srow & 1) + 4*part;
  int vrow = tid >> 4, vchunk = tid & 15;               // V^T staging
  int vws = 68*vrow + 4*vchunk;

  for (int tile = 0; tile < 16; ++tile) {
    int t0 = tile << 7;
    if (tile > 0) __syncthreads();
    *(float4*)&kt[kws] = *(const float4*)&Kb[(size_t)(t0 + srow)*64 + part*4];
    *(float4*)&vt[vws] = *(const float4*)&Vb[(size_t)vrow*1024 + (t0 >> 1) + vchunk*4];
    __syncthreads();

    // ---- scores (scalar mask loads, R6 style) ----
    float s[2][8];
    #pragma unroll
    for (int qi = 0; qi < 2; ++qi)
      #pragma unroll
      for (int i = 0; i < 4; ++i) {
        s[qi][2*i]   = maskb[(size_t)qi*PROBN + t0 + 2*nq + 32*i];
        s[qi][2*i+1] = maskb[(size_t)qi*PROBN + t0 + 2*nq + 32*i + 1];
      }
    #pragma unroll
    for (int i = 0; i < 4; ++i) {
      int p = nq + 16*i;
      float4 a0 = *(float4*)&kt[20*p];
      float4 a1 = *(float4*)&kt[20*p + 4];
      float4 b0 = *(float4*)&kt[20*p + 8];
      float4 b1 = *(float4*)&kt[20*p + 12];
      f16x2 ka[8] = {f2h(a0.x), f2h(a0.y), f2h(a0.z), f2h(a0.w),
                     f2h(a1.x), f2h(a1.y), f2h(a1.z), f2h(a1.w)};
      f16x2 kb[8] = {f2h(b0.x), f2h(b0.y), f2h(b0.z), f2h(b0.w),
                     f2h(b1.x), f2h(b1.y), f2h(b1.z), f2h(b1.w)};
      #pragma unroll
      for (int qi = 0; qi < 2; ++qi) {
        float d0 = 0.f, d1 = 0.f;
        #pragma unroll
        for (int j = 0; j < 8; ++j) {
          d0 = fdot2f(q[qi][j], ka[j], d0);
          d1 = fdot2f(q[qi][j], kb[j], d1);
        }
        s[qi][2*i]   += d0 * 0.25f;
        s[qi][2*i+1] += d1 * 0.25f;
      }
    }
    // ---- per-tile max merge + single unconditional rescale ----
    #pragma unroll
    for (int qi = 0; qi < 2; ++qi) {
      float tm = s[qi][0];
      #pragma unroll
      for (int i = 1; i < 8; ++i) tm = fmaxf(tm, s[qi][i]);
      float M = fmaxf(m[qi], tm);
      float c = __expf(m[qi] - M);
      m[qi] = M;
      l[qi] *= c;
      #pragma unroll
      for (int dd = 0; dd < 16; ++dd) acc[qi][dd] *= c;
    }
    // ---- exp + PV (pairwise fdot2 into fp32 acc) ----
    #pragma unroll
    for (int i = 0; i < 4; ++i) {
      int p = nq + 16*i;
      f16x2 wp0, wp1;
      {
        float w0 = __expf(s[0][2*i] - m[0]);
        float w1 = __expf(s[0][2*i+1] - m[0]);
        l[0] += w0 + w1;
        wp0.x = (f16)w0; wp0.y = (f16)w1;
        float u0 = __expf(s[1][2*i] - m[1]);
        float u1 = __expf(s[1][2*i+1] - m[1]);
        l[1] += u0 + u1;
        wp1.x = (f16)u0; wp1.y = (f16)u1;
      }
      #pragma unroll
      for (int dd = 0; dd < 16; ++dd) {
        f16x2 vh = f2h(vt[68*dd + p]);
        acc[0][dd] = fdot2f(wp0, vh, acc[0][dd]);
        acc[1][dd] = fdot2f(wp1, vh, acc[1][dd]);
      }
    }
  }

  // merge 16 stripes (tid bits 0..3, within wave)
  #pragma unroll
  for (int off = 1; off < 16; off <<= 1) {
    #pragma unroll
    for (int qi = 0; qi < 2; ++qi) {
      float m2 = __shfl_xor(m[qi], off);
      float l2 = __shfl_xor(l[qi], off);
      float M = fmaxf(m[qi], m2);
      float c1 = __expf(m[qi] - M), c2 = __expf(m2 - M);
      l[qi] = l[qi]*c1 + l2*c2;
      m[qi] = M;
      #pragma unroll
      for (int dd = 0; dd < 16; ++dd) {
        float a2 = __shfl_xor(acc[qi][dd], off);
        acc[qi][dd] = acc[qi][dd]*c1 + a2*c2;
      }
    }
  }
  // write: lanes nq<4, compile-time indexed via unrolled-if (rule #20)
  #pragma unroll
  for (int d4 = 0; d4 < 4; ++d4) {
    if (nq == d4) {
      #pragma unroll
      for (int qi = 0; qi < 2; ++qi) {
        float rl = 1.f / l[qi];
        *(float4*)&Op[(size_t)(prow0 + qi)*ED + h*16 + d4*4] =
          make_float4(acc[qi][4*d4+0]*rl, acc[qi][4*d4+1]*rl,
                      acc[qi][4*d4+2]*rl, acc[qi][4*d4+3]*rl);
      }
    }
  }
}

// ---------------------------------------------------------------------------
// K6: MH = OUT @ WC[b] + BC[b]   (per-batch 256x128 @ 128x128, fp32 unchanged)
// ---------------------------------------------------------------------------
__global__ __launch_bounds__(256) void k_mh(
    const float* __restrict__ Op, const float* __restrict__ WC,
    const float* __restrict__ BC, float* __restrict__ MH)
{
  __shared__ __align__(16) float As[32*132];
  __shared__ __align__(16) float Ws[128*128];
  int tid = threadIdx.x;
  int b = blockIdx.x >> 3;
  int pt = blockIdx.x & 7;
  int r0 = b*POMO + pt*32;
  #pragma unroll
  for (int j = 0; j < 4; ++j) {
    int idx = tid + j*256;
    int row = idx >> 5, c4 = (idx & 31) << 2;
    *(float4*)&As[row*132 + c4] = *(const float4*)&Op[(size_t)(r0 + row)*ED + c4];
  }
  for (int idx = tid; idx < 4096; idx += 256)
    *(float4*)&Ws[idx*4] = *(const float4*)&WC[(size_t)b*ED*ED + idx*4];
  __syncthreads();

  int colg = tid & 15, rowg = tid >> 4;
  int c0 = colg << 2;
  float4 b0 = *(const float4*)&BC[b*ED + c0];
  float4 b1 = *(const float4*)&BC[b*ED + c0 + 64];
  float acc[2][8];
  #pragma unroll
  for (int i = 0; i < 2; ++i) {
    acc[i][0] = b0.x; acc[i][1] = b0.y; acc[i][2] = b0.z; acc[i][3] = b0.w;
    acc[i][4] = b1.x; acc[i][5] = b1.y; acc[i][6] = b1.z; acc[i][7] = b1.w;
  }
  #pragma unroll 4
  for (int k = 0; k < 128; ++k) {
    float a0 = As[(rowg*2)*132 + k];
    float a1 = As[(rowg*2 + 1)*132 + k];
    float4 w0 = *(float4*)&Ws[k*128 + c0];
    float4 w1 = *(float4*)&Ws[k*128 + c0 + 64];
    acc[0][0] += a0*w0.x; acc[0][1] += a0*w0.y; acc[0][2] += a0*w0.z; acc[0][3] += a0*w0.w;
    acc[0][4] += a0*w1.x; acc[0][5] += a0*w1.y; acc[0][6] += a0*w1.z; acc[0][7] += a0*w1.w;
    acc[1][0] += a1*w0.x; acc[1][1] += a1*w0.y; acc[1][2] += a1*w0.z; acc[1][3] += a1*w0.w;
    acc[1][4] += a1*w1.x; acc[1][5] += a1*w1.y; acc[1][6] += a1*w1.z; acc[1][7] += a1*w1.w;
  }
  #pragma unroll
  for (int i = 0; i < 2; ++i) {
    size_t row = (size_t)(r0 + rowg*2 + i) * ED;
    *(float4*)&MH[row + c0]      = make_float4(acc[i][0], acc[i][1], acc[i][2], acc[i][3]);
    *(float4*)&MH[row + c0 + 64] = make_float4(acc[i][4], acc[i][5], acc[i][6], acc[i][7]);
  }
}

// ---------------------------------------------------------------------------
// K7 v3: score2 = MH @ nodes^T / sqrt(E) via f16 fdot2; probs = softmax.
// Phase 2 wave-parallel (R8 proven).
// ---------------------------------------------------------------------------
__global__ __launch_bounds__(256) void k_final(
    const float* __restrict__ MH, const float* __restrict__ Nhf,
    const float* __restrict__ mask, float* __restrict__ probs)
{
  __shared__ __align__(16) float lg[8*PROBN];     // 64 KB
  __shared__ __align__(16) float mh8[8*68];       // f16 MH rows
  int tid = threadIdx.x;
  int b = blockIdx.x >> 5;
  int p0 = (blockIdx.x & 31) * 8;
  {
    int row = tid >> 5, c4 = (tid & 31) << 2;
    float4 v = *(const float4*)&MH[(size_t)(b*POMO + p0 + row)*ED + c4];
    float2 hh; hh.x = packh2(v.x, v.y); hh.y = packh2(v.z, v.w);
    *(float2*)&mh8[row*68 + (c4 >> 1)] = hh;
  }
  __syncthreads();
  const float invs = 0.08838834764831845f;        // 1/sqrt(128)
  #pragma unroll
  for (int j = 0; j < 8; ++j) {
    int n = tid + (j << 8);
    const float* nr = &Nhf[(size_t)(b*PROBN + n)*64];
    float a[8];
    #pragma unroll
    for (int p = 0; p < 8; ++p) a[p] = 0.f;
    #pragma unroll 4
    for (int kq = 0; kq < 16; ++kq) {
      float4 nv = *(const float4*)&nr[kq*4];
      f16x2 n0 = f2h(nv.x), n1 = f2h(nv.y), n2 = f2h(nv.z), n3 = f2h(nv.w);
      #pragma unroll
      for (int p = 0; p < 8; ++p) {
        float4 mv = *(const float4*)&mh8[p*68 + kq*4];
        a[p] = fdot2f(f2h(mv.x), n0, a[p]);
        a[p] = fdot2f(f2h(mv.y), n1, a[p]);
        a[p] = fdot2f(f2h(mv.z), n2, a[p]);
        a[p] = fdot2f(f2h(mv.w), n3, a[p]);
      }
    }
    #pragma unroll
    for (int p = 0; p < 8; ++p) lg[p*PROBN + n] = a[p] * invs;
  }
  __syncthreads();

  int wid = tid >> 6, lane = tid & 63;
  #pragma unroll
  for (int pp = 0; pp < 2; ++pp) {
    int p = wid*2 + pp;
    const float* mrow = mask + (size_t)(b*POMO + p0 + p) * PROBN;
    float* prow = probs + (size_t)(b*POMO + p0 + p) * PROBN;
    float z[32];
    float mx = -3.0e38f;
    #pragma unroll
    for (int i4 = 0; i4 < 8; ++i4) {
      int n = 4*lane + 256*i4;
      float4 lv = *(const float4*)&lg[p*PROBN + n];
      float4 mv = *(const float4*)&mrow[n];
      float z0 = 10.f - 20.f/(__expf(2.f*lv.x)+1.f) + mv.x;
      float z1 = 10.f - 20.f/(__expf(2.f*lv.y)+1.f) + mv.y;
      float z2 = 10.f - 20.f/(__expf(2.f*lv.z)+1.f) + mv.z;
      float z3 = 10.f - 20.f/(__expf(2.f*lv.w)+1.f) + mv.w;
      z[4*i4+0] = z0; z[4*i4+1] = z1; z[4*i4+2] = z2; z[4*i4+3] = z3;
      mx = fmaxf(fmaxf(fmaxf(mx, z0), fmaxf(z1, z2)), z3);
    }
    #pragma unroll
    for (int off = 32; off > 0; off >>= 1) mx = fmaxf(mx, __shfl_xor(mx, off));
    float sum = 0.f;
    #pragma unroll
    for (int k = 0; k < 32; ++k) { z[k] = __expf(z[k] - mx); sum += z[k]; }
    #pragma unroll
    for (int off = 32; off > 0; off >>= 1) sum += __shfl_xor(sum, off);
    float rs = 1.f / sum;
    #pragma unroll
    for (int i4 = 0; i4 < 8; ++i4) {
      int n = 4*lane + 256*i4;
      *(float4*)&prow[n] = make_float4(z[4*i4+0]*rs, z[4*i4+1]*rs,
                                       z[4*i4+2]*rs, z[4*i4+3]*rs);
    }
  }
}

// ---------------------------------------------------------------------------
extern "C" void kernel_launch(void* const* d_in, const int* in_sizes, int n_in,
                              void* d_out, int out_size, void* d_ws, size_t ws_size,
                              hipStream_t stream)
{
  const float* nodes  = (const float*)d_in[0];
  const float* last   = (const float*)d_in[1];
  const float* mid    = (const float*)d_in[2];
  const float* loadv  = (const float*)d_in[3];
  const float* mask   = (const float*)d_in[4];
  const float* Wq     = (const float*)d_in[5];
  const float* Wk     = (const float*)d_in[6];
  const float* Wv     = (const float*)d_in[7];
  const float* eW     = (const float*)d_in[8];
  const float* eB     = (const float*)d_in[9];
  const float* w_gate = (const float*)d_in[10];
  float* out = (float*)d_out;
  float* ws  = (float*)d_ws;

  k_gating<<<1, 128, 0, stream>>>(mid, w_gate, ws + WS_GATES, out + BB*POMO*PROBN);
  k_experts<<<128, 256, 0, stream>>>(ws + WS_GATES, eW, eB, ws + WS_WC, ws + WS_BC);
  k_kv<<<512, 256, 0, stream>>>(nodes, Wk, Wv, ws + WS_KH, ws + WS_VHT, ws + WS_NH);
  k_q<<<128, 256, 0, stream>>>(last, loadv, Wq, ws + WS_QH);
  k_attn<<<dim3(128, 8), 256, 0, stream>>>(ws + WS_KH, ws + WS_VHT, ws + WS_QH, mask, ws + WS_OUT);
  k_mh<<<128, 256, 0, stream>>>(ws + WS_OUT, ws + WS_WC, ws + WS_BC, ws + WS_MH);
  k_final<<<512, 256, 0, stream>>>(ws + WS_MH, ws + WS_NH, mask, out);
}

// Round 10
// 182.180 us; speedup vs baseline: 1.7803x; 1.0576x over previous
//
#include <hip/hip_runtime.h>
#include <math.h>

#define BB    16
#define PROBN 2048
#define POMO  256
#define ED    128
#define HN    8
#define DDIM  16
#define NEXP  8

typedef _Float16 f16;
typedef f16 f16x2 __attribute__((ext_vector_type(2)));

__device__ __forceinline__ f16x2 f2h(float f) {
  union U { float f; f16x2 h; } u; u.f = f; return u.h;
}
__device__ __forceinline__ float packh2(float a, float b) {
  union U { float f; f16x2 h; } u; u.h.x = (f16)a; u.h.y = (f16)b; return u.f;
}
__device__ __forceinline__ float fdot2f(f16x2 a, f16x2 b, float c) {
#if __has_builtin(__builtin_amdgcn_fdot2)
  return __builtin_amdgcn_fdot2(a, b, c, false);
#else
  return c + (float)a.x * (float)b.x + (float)a.y * (float)b.y;
#endif
}

// ws float offsets (f16 arrays addressed as float*; total ~9.6M floats = 38MB)
#define WS_KH    0                        // f16 K [b][n][h*16+d]    (2,097,152 floats)
#define WS_VHT   (WS_KH + 2097152)        // f16 V^T [b][h*16+d][n]  (2,097,152)
#define WS_NH    (WS_VHT + 2097152)       // f16 nodes [b][n][d]     (2,097,152)
#define WS_QH    (WS_NH + 2097152)        // f16 Q [b*POMO][d]       (262,144)
#define WS_OUT   (WS_QH + 262144)         // f16 attn out [row][64f] (262,144)
#define WS_MH    (WS_OUT + 262144)        // fp32 MoE out            (524,288)
#define WS_WC    (WS_MH + 524288)         // f16 WC pairs [b][p][c]  (131,072)
#define WS_BC    (WS_WC + 131072)         // fp32 combined bias      (2,048)
#define WS_GATES (WS_BC + 2048)

// ---------------------------------------------------------------------------
// K1: gating (top-2 softmax), gates -> ws, moe_loss -> d_out tail.
// STAYS FP32-EXACT: moe_loss is the only strictly-checked output (thr 1.39e-2).
// ---------------------------------------------------------------------------
__global__ __launch_bounds__(128) void k_gating(
    const float* __restrict__ mid, const float* __restrict__ w_gate,
    float* __restrict__ gates_ws, float* __restrict__ moe_out)
{
  __shared__ float lg[BB][NEXP];
  __shared__ float gt[BB][NEXP];
  int t = threadIdx.x;
  {
    int b = t >> 3, e = t & 7;
    float acc = 0.f;
    #pragma unroll 8
    for (int k = 0; k < ED; ++k) acc += mid[b*ED + k] * w_gate[k*NEXP + e];
    lg[b][e] = acc;
  }
  __syncthreads();
  if (t < BB) {
    int b = t;
    int i1 = 0; float v1 = lg[b][0];
    #pragma unroll
    for (int e = 1; e < NEXP; ++e) if (lg[b][e] > v1) { v1 = lg[b][e]; i1 = e; }
    int i2 = -1; float v2 = -3.0e38f;
    #pragma unroll
    for (int e = 0; e < NEXP; ++e) if (e != i1 && lg[b][e] > v2) { v2 = lg[b][e]; i2 = e; }
    float e2 = __expf(v2 - v1);          // <= 1
    float g1 = 1.f / (1.f + e2);
    #pragma unroll
    for (int e = 0; e < NEXP; ++e) gt[b][e] = 0.f;
    gt[b][i1] = g1;
    gt[b][i2] = e2 * g1;
  }
  __syncthreads();
  if (t < BB*NEXP) gates_ws[t] = gt[t >> 3][t & 7];
  if (t == 0) {
    float imp[NEXP], ldc[NEXP];
    #pragma unroll
    for (int e = 0; e < NEXP; ++e) { imp[e] = 0.f; ldc[e] = 0.f; }
    for (int b = 0; b < BB; ++b)
      #pragma unroll
      for (int e = 0; e < NEXP; ++e) {
        float g = gt[b][e];
        imp[e] += g;
        if (g > 0.f) ldc[e] += 1.f;
      }
    float im = 0.f, lm = 0.f;
    #pragma unroll
    for (int e = 0; e < NEXP; ++e) { im += imp[e]; lm += ldc[e]; }
    im *= 0.125f; lm *= 0.125f;
    float iv = 0.f, lv = 0.f;
    #pragma unroll
    for (int e = 0; e < NEXP; ++e) {
      float a = imp[e] - im; iv += a*a;
      float c = ldc[e] - lm; lv += c*c;
    }
    iv *= 0.125f; lv *= 0.125f;
    moe_out[0] = iv / (im*im + 1e-10f) + lv / (lm*lm + 1e-10f);
  }
}

// ---------------------------------------------------------------------------
// K2 v3: WCh[b] = f16 (k,k+1)-pairs of sum_e g_e*expert_W[e]; BC fp32.
// grid (b,tile) = 128 blocks, 1024 packed floats per tile.
// ---------------------------------------------------------------------------
__global__ __launch_bounds__(256) void k_experts(
    const float* __restrict__ gates, const float* __restrict__ eW,
    const float* __restrict__ eB, float* __restrict__ WCh, float* __restrict__ BC)
{
  __shared__ float g[NEXP];
  int tid = threadIdx.x;
  int b = blockIdx.x >> 3;
  int tile = blockIdx.x & 7;           // 8 tiles of 1024 packed floats
  if (tid < NEXP) g[tid] = gates[b*NEXP + tid];
  __syncthreads();
  int i0 = tile * 1024;
  #pragma unroll
  for (int j = 0; j < 4; ++j) {
    int pi = i0 + tid + j*256;         // packed index: p*128 + c
    int k2 = (pi >> 7) << 1;           // 2p
    int c  = pi & 127;
    float a0 = 0.f, a1 = 0.f;
    #pragma unroll
    for (int e = 0; e < NEXP; ++e) {
      a0 += g[e] * eW[e*ED*ED + k2*ED + c];
      a1 += g[e] * eW[e*ED*ED + (k2+1)*ED + c];
    }
    WCh[(size_t)b*8192 + pi] = packh2(a0, a1);
  }
  if (tile == 0 && tid < ED) {
    float a = 0.f;
    #pragma unroll
    for (int e = 0; e < NEXP; ++e) a += g[e] * eB[e*ED + tid];
    BC[b*ED + tid] = a;
  }
}

// ---------------------------------------------------------------------------
// K3 v4: K/V projection with f16 fdot2 inner loop (R9-proven recipe).
// A-tile f16 pairs in LDS (packed once, reused for Nhf); W staged as f16
// (k,k+1)-pairs. 1024 fdot2 per k-tile (was 2048 fp32 FMA). LDS 33KB.
// ---------------------------------------------------------------------------
__global__ __launch_bounds__(256) void k_kv(
    const float* __restrict__ nodes, const float* __restrict__ Wk,
    const float* __restrict__ Wv, float* __restrict__ Khf,
    float* __restrict__ VhTf, float* __restrict__ Nhf)
{
  __shared__ __align__(16) float Ash[64*66];     // 64 rows x (64 d-pairs + 2 pad)
  __shared__ __align__(16) float Wkp[16*128];    // f16 pairs [p][c]
  __shared__ __align__(16) float Wvp[16*128];
  int tid = threadIdx.x;
  int r0 = blockIdx.x * 64;
  #pragma unroll
  for (int j = 0; j < 8; ++j) {
    int idx = tid + j*256;
    int row = idx >> 5, c4 = (idx & 31) << 2;
    float4 v = *(const float4*)&nodes[(size_t)(r0 + row)*ED + c4];
    float2 nh; nh.x = packh2(v.x, v.y); nh.y = packh2(v.z, v.w);
    *(float2*)&Ash[row*66 + (c4 >> 1)] = nh;
    *(float2*)&Nhf[(size_t)(r0 + row)*64 + (c4 >> 1)] = nh;
  }
  int colg = tid & 15, rowg = tid >> 4;
  int c0 = colg << 2;              // cols c0..c0+3 and c0+64..c0+67
  float accK[4][8], accV[4][8];
  #pragma unroll
  for (int i = 0; i < 4; ++i)
    #pragma unroll
    for (int j = 0; j < 8; ++j) { accK[i][j] = 0.f; accV[i][j] = 0.f; }

  for (int kk = 0; kk < 128; kk += 32) {
    __syncthreads();
    #pragma unroll
    for (int j = 0; j < 2; ++j) {
      int wi = tid + j*256;
      int p = wi >> 5, c4 = (wi & 31) << 2;
      float4 ka = *(const float4*)&Wk[(kk + 2*p)*ED + c4];
      float4 kb = *(const float4*)&Wk[(kk + 2*p + 1)*ED + c4];
      float4 pk; pk.x = packh2(ka.x, kb.x); pk.y = packh2(ka.y, kb.y);
      pk.z = packh2(ka.z, kb.z); pk.w = packh2(ka.w, kb.w);
      *(float4*)&Wkp[p*128 + c4] = pk;
      float4 va = *(const float4*)&Wv[(kk + 2*p)*ED + c4];
      float4 vb = *(const float4*)&Wv[(kk + 2*p + 1)*ED + c4];
      float4 pv; pv.x = packh2(va.x, vb.x); pv.y = packh2(va.y, vb.y);
      pv.z = packh2(va.z, vb.z); pv.w = packh2(va.w, vb.w);
      *(float4*)&Wvp[p*128 + c4] = pv;
    }
    __syncthreads();
    #pragma unroll 4
    for (int p = 0; p < 16; ++p) {
      float ap[4];
      #pragma unroll
      for (int i = 0; i < 4; ++i) ap[i] = Ash[(rowg*4 + i)*66 + (kk >> 1) + p];
      float4 wk0 = *(float4*)&Wkp[p*128 + c0];
      float4 wk1 = *(float4*)&Wkp[p*128 + c0 + 64];
      float4 wv0 = *(float4*)&Wvp[p*128 + c0];
      float4 wv1 = *(float4*)&Wvp[p*128 + c0 + 64];
      #pragma unroll
      for (int i = 0; i < 4; ++i) {
        f16x2 ai = f2h(ap[i]);
        accK[i][0] = fdot2f(ai, f2h(wk0.x), accK[i][0]);
        accK[i][1] = fdot2f(ai, f2h(wk0.y), accK[i][1]);
        accK[i][2] = fdot2f(ai, f2h(wk0.z), accK[i][2]);
        accK[i][3] = fdot2f(ai, f2h(wk0.w), accK[i][3]);
        accK[i][4] = fdot2f(ai, f2h(wk1.x), accK[i][4]);
        accK[i][5] = fdot2f(ai, f2h(wk1.y), accK[i][5]);
        accK[i][6] = fdot2f(ai, f2h(wk1.z), accK[i][6]);
        accK[i][7] = fdot2f(ai, f2h(wk1.w), accK[i][7]);
        accV[i][0] = fdot2f(ai, f2h(wv0.x), accV[i][0]);
        accV[i][1] = fdot2f(ai, f2h(wv0.y), accV[i][1]);
        accV[i][2] = fdot2f(ai, f2h(wv0.z), accV[i][2]);
        accV[i][3] = fdot2f(ai, f2h(wv0.w), accV[i][3]);
        accV[i][4] = fdot2f(ai, f2h(wv1.x), accV[i][4]);
        accV[i][5] = fdot2f(ai, f2h(wv1.y), accV[i][5]);
        accV[i][6] = fdot2f(ai, f2h(wv1.z), accV[i][6]);
        accV[i][7] = fdot2f(ai, f2h(wv1.w), accV[i][7]);
      }
    }
  }
  // K: f16 row-major
  #pragma unroll
  for (int i = 0; i < 4; ++i) {
    size_t row = (size_t)(r0 + rowg*4 + i);
    float2 k0; k0.x = packh2(accK[i][0], accK[i][1]); k0.y = packh2(accK[i][2], accK[i][3]);
    float2 k1; k1.x = packh2(accK[i][4], accK[i][5]); k1.y = packh2(accK[i][6], accK[i][7]);
    *(float2*)&Khf[row*64 + (c0 >> 1)]      = k0;
    *(float2*)&Khf[row*64 + (c0 >> 1) + 32] = k1;
  }
  // V: f16 transposed [b][col][n] — thread's 4 rows are consecutive n
  int bb = r0 >> 11;
  int nn0 = (r0 & 2047) + rowg*4;
  #pragma unroll
  for (int j = 0; j < 8; ++j) {
    int col = (j < 4) ? (c0 + j) : (c0 + 60 + j);
    float2 vv; vv.x = packh2(accV[0][j], accV[1][j]); vv.y = packh2(accV[2][j], accV[3][j]);
    *(float2*)&VhTf[((size_t)bb*128 + col)*1024 + (nn0 >> 1)] = vv;
  }
}

// ---------------------------------------------------------------------------
// K4: Q = [last, load] @ Wq_last, fp32 compute, f16 output (R9 proven)
// ---------------------------------------------------------------------------
__global__ __launch_bounds__(256) void k_q(
    const float* __restrict__ last, const float* __restrict__ loadv,
    const float* __restrict__ Wq, float* __restrict__ Qhf)
{
  __shared__ __align__(16) float As[32*132];
  __shared__ __align__(16) float Ws[129*128];
  int tid = threadIdx.x;
  int r0 = blockIdx.x * 32;
  #pragma unroll
  for (int j = 0; j < 4; ++j) {
    int idx = tid + j*256;
    int row = idx >> 5, c4 = (idx & 31) << 2;
    *(float4*)&As[row*132 + c4] = *(const float4*)&last[(size_t)(r0 + row)*ED + c4];
  }
  if (tid < 32) As[tid*132 + 128] = loadv[r0 + tid];
  for (int idx = tid; idx < 4128; idx += 256)
    *(float4*)&Ws[idx*4] = *(const float4*)&Wq[idx*4];
  __syncthreads();

  int colg = tid & 15, rowg = tid >> 4;
  int c0 = colg << 2;
  float acc[2][8];
  #pragma unroll
  for (int i = 0; i < 2; ++i)
    #pragma unroll
    for (int j = 0; j < 8; ++j) acc[i][j] = 0.f;
  #pragma unroll 4
  for (int k = 0; k < 129; ++k) {
    float a0 = As[(rowg*2)*132 + k];
    float a1 = As[(rowg*2 + 1)*132 + k];
    float4 w0 = *(float4*)&Ws[k*128 + c0];
    float4 w1 = *(float4*)&Ws[k*128 + c0 + 64];
    acc[0][0] += a0*w0.x; acc[0][1] += a0*w0.y; acc[0][2] += a0*w0.z; acc[0][3] += a0*w0.w;
    acc[0][4] += a0*w1.x; acc[0][5] += a0*w1.y; acc[0][6] += a0*w1.z; acc[0][7] += a0*w1.w;
    acc[1][0] += a1*w0.x; acc[1][1] += a1*w0.y; acc[1][2] += a1*w0.z; acc[1][3] += a1*w0.w;
    acc[1][4] += a1*w1.x; acc[1][5] += a1*w1.y; acc[1][6] += a1*w1.z; acc[1][7] += a1*w1.w;
  }
  #pragma unroll
  for (int i = 0; i < 2; ++i) {
    size_t row = (size_t)(r0 + rowg*2 + i);
    float2 q0; q0.x = packh2(acc[i][0], acc[i][1]); q0.y = packh2(acc[i][2], acc[i][3]);
    float2 q1; q1.x = packh2(acc[i][4], acc[i][5]); q1.y = packh2(acc[i][6], acc[i][7]);
    *(float2*)&Qhf[row*64 + (c0 >> 1)]      = q0;
    *(float2*)&Qhf[row*64 + (c0 >> 1) + 32] = q1;
  }
}

// ---------------------------------------------------------------------------
// K5 v8 = R9's proven f16 attention; ONLY the epilogue changed (packs f16 Op).
// Main loop FROZEN. DO NOT add: reg prefetch, vectorized mask map, defer-max,
// bigger KVBLK (R2/R4/R5/R7 all spilled acc -> GB-scale scratch).
// Guard: WRITE_SIZE must stay ~1MB.
// ---------------------------------------------------------------------------
__global__ __launch_bounds__(256, 4) void k_attn(
    const float* __restrict__ Khf, const float* __restrict__ VhTf,
    const float* __restrict__ Qhf, const float* __restrict__ mask,
    float* __restrict__ Oph)
{
  __shared__ __align__(16) float kt[64*20];   // 64 key-pairs x (32 halfs + pad)
  __shared__ __align__(16) float vt[16*68];   // 16 d-rows x (128 key halfs + pad)
  int tid = threadIdx.x;
  int h = blockIdx.x & 7, b = blockIdx.x >> 3;
  int ph = blockIdx.y;
  int nq = tid & 15;
  int pg = tid >> 4;
  int prow0 = b*POMO + ph*32 + pg*2;
  const float* maskb = mask + (size_t)prow0 * PROBN;
  const float* Kb = Khf + (size_t)b*PROBN*64 + h*8;        // float units
  const float* Vb = VhTf + ((size_t)b*128 + h*16)*1024;    // d-row stride 1024 floats

  f16x2 q[2][8];
  #pragma unroll
  for (int qi = 0; qi < 2; ++qi) {
    const float* qp = Qhf + (size_t)(prow0 + qi)*64 + h*8;
    float4 t0 = *(const float4*)&qp[0];
    float4 t1 = *(const float4*)&qp[4];
    q[qi][0] = f2h(t0.x); q[qi][1] = f2h(t0.y); q[qi][2] = f2h(t0.z); q[qi][3] = f2h(t0.w);
    q[qi][4] = f2h(t1.x); q[qi][5] = f2h(t1.y); q[qi][6] = f2h(t1.z); q[qi][7] = f2h(t1.w);
  }
  float m[2], l[2], acc[2][16];
  #pragma unroll
  for (int qi = 0; qi < 2; ++qi) {
    m[qi] = -1.0e30f; l[qi] = 0.f;
    #pragma unroll
    for (int dd = 0; dd < 16; ++dd) acc[qi][dd] = 0.f;
  }

  int srow = tid >> 1, part = tid & 1;                  // K staging: 2 thr/row
  int kws = 20*(srow >> 1) + 8*(srow & 1) + 4*part;
  int vrow = tid >> 4, vchunk = tid & 15;               // V^T staging
  int vws = 68*vrow + 4*vchunk;

  for (int tile = 0; tile < 16; ++tile) {
    int t0 = tile << 7;
    if (tile > 0) __syncthreads();
    *(float4*)&kt[kws] = *(const float4*)&Kb[(size_t)(t0 + srow)*64 + part*4];
    *(float4*)&vt[vws] = *(const float4*)&Vb[(size_t)vrow*1024 + (t0 >> 1) + vchunk*4];
    __syncthreads();

    // ---- scores (scalar mask loads, R6 style) ----
    float s[2][8];
    #pragma unroll
    for (int qi = 0; qi < 2; ++qi)
      #pragma unroll
      for (int i = 0; i < 4; ++i) {
        s[qi][2*i]   = maskb[(size_t)qi*PROBN + t0 + 2*nq + 32*i];
        s[qi][2*i+1] = maskb[(size_t)qi*PROBN + t0 + 2*nq + 32*i + 1];
      }
    #pragma unroll
    for (int i = 0; i < 4; ++i) {
      int p = nq + 16*i;
      float4 a0 = *(float4*)&kt[20*p];
      float4 a1 = *(float4*)&kt[20*p + 4];
      float4 b0 = *(float4*)&kt[20*p + 8];
      float4 b1 = *(float4*)&kt[20*p + 12];
      f16x2 ka[8] = {f2h(a0.x), f2h(a0.y), f2h(a0.z), f2h(a0.w),
                     f2h(a1.x), f2h(a1.y), f2h(a1.z), f2h(a1.w)};
      f16x2 kb[8] = {f2h(b0.x), f2h(b0.y), f2h(b0.z), f2h(b0.w),
                     f2h(b1.x), f2h(b1.y), f2h(b1.z), f2h(b1.w)};
      #pragma unroll
      for (int qi = 0; qi < 2; ++qi) {
        float d0 = 0.f, d1 = 0.f;
        #pragma unroll
        for (int j = 0; j < 8; ++j) {
          d0 = fdot2f(q[qi][j], ka[j], d0);
          d1 = fdot2f(q[qi][j], kb[j], d1);
        }
        s[qi][2*i]   += d0 * 0.25f;
        s[qi][2*i+1] += d1 * 0.25f;
      }
    }
    // ---- per-tile max merge + single unconditional rescale ----
    #pragma unroll
    for (int qi = 0; qi < 2; ++qi) {
      float tm = s[qi][0];
      #pragma unroll
      for (int i = 1; i < 8; ++i) tm = fmaxf(tm, s[qi][i]);
      float M = fmaxf(m[qi], tm);
      float c = __expf(m[qi] - M);
      m[qi] = M;
      l[qi] *= c;
      #pragma unroll
      for (int dd = 0; dd < 16; ++dd) acc[qi][dd] *= c;
    }
    // ---- exp + PV (pairwise fdot2 into fp32 acc) ----
    #pragma unroll
    for (int i = 0; i < 4; ++i) {
      int p = nq + 16*i;
      f16x2 wp0, wp1;
      {
        float w0 = __expf(s[0][2*i] - m[0]);
        float w1 = __expf(s[0][2*i+1] - m[0]);
        l[0] += w0 + w1;
        wp0.x = (f16)w0; wp0.y = (f16)w1;
        float u0 = __expf(s[1][2*i] - m[1]);
        float u1 = __expf(s[1][2*i+1] - m[1]);
        l[1] += u0 + u1;
        wp1.x = (f16)u0; wp1.y = (f16)u1;
      }
      #pragma unroll
      for (int dd = 0; dd < 16; ++dd) {
        f16x2 vh = f2h(vt[68*dd + p]);
        acc[0][dd] = fdot2f(wp0, vh, acc[0][dd]);
        acc[1][dd] = fdot2f(wp1, vh, acc[1][dd]);
      }
    }
  }

  // merge 16 stripes (tid bits 0..3, within wave)
  #pragma unroll
  for (int off = 1; off < 16; off <<= 1) {
    #pragma unroll
    for (int qi = 0; qi < 2; ++qi) {
      float m2 = __shfl_xor(m[qi], off);
      float l2 = __shfl_xor(l[qi], off);
      float M = fmaxf(m[qi], m2);
      float c1 = __expf(m[qi] - M), c2 = __expf(m2 - M);
      l[qi] = l[qi]*c1 + l2*c2;
      m[qi] = M;
      #pragma unroll
      for (int dd = 0; dd < 16; ++dd) {
        float a2 = __shfl_xor(acc[qi][dd], off);
        acc[qi][dd] = acc[qi][dd]*c1 + a2*c2;
      }
    }
  }
  // write f16-packed: lanes nq<4, compile-time indexed (rule #20)
  #pragma unroll
  for (int d4 = 0; d4 < 4; ++d4) {
    if (nq == d4) {
      #pragma unroll
      for (int qi = 0; qi < 2; ++qi) {
        float rl = 1.f / l[qi];
        float2 o;
        o.x = packh2(acc[qi][4*d4+0]*rl, acc[qi][4*d4+1]*rl);
        o.y = packh2(acc[qi][4*d4+2]*rl, acc[qi][4*d4+3]*rl);
        *(float2*)&Oph[(size_t)(prow0 + qi)*64 + h*8 + d4*2] = o;
      }
    }
  }
}

// ---------------------------------------------------------------------------
// K6 v3: MH = Oph @ WCh[b] + BC[b], f16 fdot2, grid 256 (16-row tiles —
// was 128 blocks = half the CUs idle). MH output stays fp32.
// ---------------------------------------------------------------------------
__global__ __launch_bounds__(256) void k_mh(
    const float* __restrict__ Oph, const float* __restrict__ WCh,
    const float* __restrict__ BC, float* __restrict__ MH)
{
  __shared__ __align__(16) float Ash[16*66];    // 16 rows x 64 d-pairs (+pad)
  __shared__ __align__(16) float Wp[64*128];    // 32KB f16 pairs [p][c]
  int tid = threadIdx.x;
  int b = blockIdx.x >> 4;
  int pt = blockIdx.x & 15;
  int r0 = b*POMO + pt*16;
  {
    int row = tid >> 4, c4 = (tid & 15) << 2;
    *(float4*)&Ash[row*66 + c4] = *(const float4*)&Oph[(size_t)(r0 + row)*64 + c4];
  }
  #pragma unroll
  for (int j = 0; j < 8; ++j) {
    int wi = tid + j*256;
    *(float4*)&Wp[wi*4] = *(const float4*)&WCh[(size_t)b*8192 + wi*4];
  }
  __syncthreads();

  int colg = tid & 15, rowg = tid >> 4;
  int c0 = colg << 2;
  float4 b0 = *(const float4*)&BC[b*ED + c0];
  float4 b1 = *(const float4*)&BC[b*ED + c0 + 64];
  float acc[8] = {b0.x, b0.y, b0.z, b0.w, b1.x, b1.y, b1.z, b1.w};
  #pragma unroll 4
  for (int p = 0; p < 64; ++p) {
    f16x2 a = f2h(Ash[rowg*66 + p]);
    float4 w0 = *(float4*)&Wp[p*128 + c0];
    float4 w1 = *(float4*)&Wp[p*128 + c0 + 64];
    acc[0] = fdot2f(a, f2h(w0.x), acc[0]);
    acc[1] = fdot2f(a, f2h(w0.y), acc[1]);
    acc[2] = fdot2f(a, f2h(w0.z), acc[2]);
    acc[3] = fdot2f(a, f2h(w0.w), acc[3]);
    acc[4] = fdot2f(a, f2h(w1.x), acc[4]);
    acc[5] = fdot2f(a, f2h(w1.y), acc[5]);
    acc[6] = fdot2f(a, f2h(w1.z), acc[6]);
    acc[7] = fdot2f(a, f2h(w1.w), acc[7]);
  }
  size_t row = (size_t)(r0 + rowg) * ED;
  *(float4*)&MH[row + c0]      = make_float4(acc[0], acc[1], acc[2], acc[3]);
  *(float4*)&MH[row + c0 + 64] = make_float4(acc[4], acc[5], acc[6], acc[7]);
}

// ---------------------------------------------------------------------------
// K7: score2 = MH @ nodes^T / sqrt(E) via f16 fdot2; probs = softmax.
// Phase 2 wave-parallel (R8/R9 proven).
// ---------------------------------------------------------------------------
__global__ __launch_bounds__(256) void k_final(
    const float* __restrict__ MH, const float* __restrict__ Nhf,
    const float* __restrict__ mask, float* __restrict__ probs)
{
  __shared__ __align__(16) float lg[8*PROBN];     // 64 KB
  __shared__ __align__(16) float mh8[8*68];       // f16 MH rows
  int tid = threadIdx.x;
  int b = blockIdx.x >> 5;
  int p0 = (blockIdx.x & 31) * 8;
  {
    int row = tid >> 5, c4 = (tid & 31) << 2;
    float4 v = *(const float4*)&MH[(size_t)(b*POMO + p0 + row)*ED + c4];
    float2 hh; hh.x = packh2(v.x, v.y); hh.y = packh2(v.z, v.w);
    *(float2*)&mh8[row*68 + (c4 >> 1)] = hh;
  }
  __syncthreads();
  const float invs = 0.08838834764831845f;        // 1/sqrt(128)
  #pragma unroll
  for (int j = 0; j < 8; ++j) {
    int n = tid + (j << 8);
    const float* nr = &Nhf[(size_t)(b*PROBN + n)*64];
    float a[8];
    #pragma unroll
    for (int p = 0; p < 8; ++p) a[p] = 0.f;
    #pragma unroll 4
    for (int kq = 0; kq < 16; ++kq) {
      float4 nv = *(const float4*)&nr[kq*4];
      f16x2 n0 = f2h(nv.x), n1 = f2h(nv.y), n2 = f2h(nv.z), n3 = f2h(nv.w);
      #pragma unroll
      for (int p = 0; p < 8; ++p) {
        float4 mv = *(const float4*)&mh8[p*68 + kq*4];
        a[p] = fdot2f(f2h(mv.x), n0, a[p]);
        a[p] = fdot2f(f2h(mv.y), n1, a[p]);
        a[p] = fdot2f(f2h(mv.z), n2, a[p]);
        a[p] = fdot2f(f2h(mv.w), n3, a[p]);
      }
    }
    #pragma unroll
    for (int p = 0; p < 8; ++p) lg[p*PROBN + n] = a[p] * invs;
  }
  __syncthreads();

  int wid = tid >> 6, lane = tid & 63;
  #pragma unroll
  for (int pp = 0; pp < 2; ++pp) {
    int p = wid*2 + pp;
    const float* mrow = mask + (size_t)(b*POMO + p0 + p) * PROBN;
    float* prow = probs + (size_t)(b*POMO + p0 + p) * PROBN;
    float z[32];
    float mx = -3.0e38f;
    #pragma unroll
    for (int i4 = 0; i4 < 8; ++i4) {
      int n = 4*lane + 256*i4;
      float4 lv = *(const float4*)&lg[p*PROBN + n];
      float4 mv = *(const float4*)&mrow[n];
      float z0 = 10.f - 20.f/(__expf(2.f*lv.x)+1.f) + mv.x;
      float z1 = 10.f - 20.f/(__expf(2.f*lv.y)+1.f) + mv.y;
      float z2 = 10.f - 20.f/(__expf(2.f*lv.z)+1.f) + mv.z;
      float z3 = 10.f - 20.f/(__expf(2.f*lv.w)+1.f) + mv.w;
      z[4*i4+0] = z0; z[4*i4+1] = z1; z[4*i4+2] = z2; z[4*i4+3] = z3;
      mx = fmaxf(fmaxf(fmaxf(mx, z0), fmaxf(z1, z2)), z3);
    }
    #pragma unroll
    for (int off = 32; off > 0; off >>= 1) mx = fmaxf(mx, __shfl_xor(mx, off));
    float sum = 0.f;
    #pragma unroll
    for (int k = 0; k < 32; ++k) { z[k] = __expf(z[k] - mx); sum += z[k]; }
    #pragma unroll
    for (int off = 32; off > 0; off >>= 1) sum += __shfl_xor(sum, off);
    float rs = 1.f / sum;
    #pragma unroll
    for (int i4 = 0; i4 < 8; ++i4) {
      int n = 4*lane + 256*i4;
      *(float4*)&prow[n] = make_float4(z[4*i4+0]*rs, z[4*i4+1]*rs,
                                       z[4*i4+2]*rs, z[4*i4+3]*rs);
    }
  }
}

// ---------------------------------------------------------------------------
extern "C" void kernel_launch(void* const* d_in, const int* in_sizes, int n_in,
                              void* d_out, int out_size, void* d_ws, size_t ws_size,
                              hipStream_t stream)
{
  const float* nodes  = (const float*)d_in[0];
  const float* last   = (const float*)d_in[1];
  const float* mid    = (const float*)d_in[2];
  const float* loadv  = (const float*)d_in[3];
  const float* mask   = (const float*)d_in[4];
  const float* Wq     = (const float*)d_in[5];
  const float* Wk     = (const float*)d_in[6];
  const float* Wv     = (const float*)d_in[7];
  const float* eW     = (const float*)d_in[8];
  const float* eB     = (const float*)d_in[9];
  const float* w_gate = (const float*)d_in[10];
  float* out = (float*)d_out;
  float* ws  = (float*)d_ws;

  k_gating<<<1, 128, 0, stream>>>(mid, w_gate, ws + WS_GATES, out + BB*POMO*PROBN);
  k_experts<<<128, 256, 0, stream>>>(ws + WS_GATES, eW, eB, ws + WS_WC, ws + WS_BC);
  k_kv<<<512, 256, 0, stream>>>(nodes, Wk, Wv, ws + WS_KH, ws + WS_VHT, ws + WS_NH);
  k_q<<<128, 256, 0, stream>>>(last, loadv, Wq, ws + WS_QH);
  k_attn<<<dim3(128, 8), 256, 0, stream>>>(ws + WS_KH, ws + WS_VHT, ws + WS_QH, mask, ws + WS_OUT);
  k_mh<<<256, 256, 0, stream>>>(ws + WS_OUT, ws + WS_WC, ws + WS_BC, ws + WS_MH);
  k_final<<<512, 256, 0, stream>>>(ws + WS_MH, ws + WS_NH, mask, out);
}